// Round 1
// baseline (3010.245 us; speedup 1.0000x reference)
//
#include <hip/hip_runtime.h>
#include <cstdint>
#include <cstddef>

#define L_DIM 4096
#define D_DIM 512
#define C_DIM 512
#define CIN   256
#define BATCH 16

// ---------------------------------------------------------------------------
// Projection GEMM: Y[b,o,s] = sum_c W[o,c] * X[b,c,s] + bias[o]
// X = concat(input_1, input_2) along c. Tile 128x128, BK=16, 8x8 microtile.
// grid: (L/128=32, 512/128=4, B*3=48), block 256
// ---------------------------------------------------------------------------
__global__ __launch_bounds__(256) void proj_gemm(
    const float* __restrict__ x1, const float* __restrict__ x2,
    const float* __restrict__ Wq, const float* __restrict__ bq,
    const float* __restrict__ Wk, const float* __restrict__ bk,
    const float* __restrict__ Wv, const float* __restrict__ bv,
    float* __restrict__ qout, float* __restrict__ kout, float* __restrict__ vout)
{
    const int z = blockIdx.z;
    const int b = z / 3, w = z % 3;
    const float* Wm = (w == 0) ? Wq : (w == 1) ? Wk : Wv;
    const float* bm = (w == 0) ? bq : (w == 1) ? bk : bv;
    float* outp = ((w == 0) ? qout : (w == 1) ? kout : vout)
                  + (size_t)b * ((size_t)D_DIM * L_DIM);
    const float* X1 = x1 + (size_t)b * CIN * L_DIM;
    const float* X2 = x2 + (size_t)b * CIN * L_DIM;

    const int n0 = blockIdx.x * 128;
    const int m0 = blockIdx.y * 128;

    __shared__ float As[16][132];   // As[c][m]  (132*4 = 528 B rows, 16B aligned)
    __shared__ float Bs[16][128];   // Bs[c][n]

    const int tid = threadIdx.x;
    const int tx = tid & 15, ty = tid >> 4;

    float acc[8][8];
    #pragma unroll
    for (int i = 0; i < 8; i++)
        #pragma unroll
        for (int j = 0; j < 8; j++) acc[i][j] = 0.f;

    for (int k0 = 0; k0 < C_DIM; k0 += 16) {
        // A tile: W[m0..+127][k0..+15] -> transposed into As
        #pragma unroll
        for (int t = 0; t < 2; t++) {
            int idx = tid + t * 256;          // 0..511 float4 slots
            int m = idx >> 2, cq = idx & 3;
            float4 a4 = *(const float4*)&Wm[(size_t)(m0 + m) * C_DIM + k0 + cq * 4];
            As[cq * 4 + 0][m] = a4.x; As[cq * 4 + 1][m] = a4.y;
            As[cq * 4 + 2][m] = a4.z; As[cq * 4 + 3][m] = a4.w;
        }
        // B tile: X[k0+kk][n0..+127]
        #pragma unroll
        for (int t = 0; t < 2; t++) {
            int idx = tid + t * 256;
            int kk = idx >> 5, nq = idx & 31;
            int c = k0 + kk;
            const float* src = (c < CIN) ? (X1 + (size_t)c * L_DIM + n0 + nq * 4)
                                         : (X2 + (size_t)(c - CIN) * L_DIM + n0 + nq * 4);
            *(float4*)&Bs[kk][nq * 4] = *(const float4*)src;
        }
        __syncthreads();
        #pragma unroll
        for (int kk = 0; kk < 16; kk++) {
            float a[8], bb[8];
            *(float4*)&a[0]  = *(float4*)&As[kk][ty * 8];
            *(float4*)&a[4]  = *(float4*)&As[kk][ty * 8 + 4];
            *(float4*)&bb[0] = *(float4*)&Bs[kk][tx * 8];
            *(float4*)&bb[4] = *(float4*)&Bs[kk][tx * 8 + 4];
            #pragma unroll
            for (int i = 0; i < 8; i++)
                #pragma unroll
                for (int j = 0; j < 8; j++)
                    acc[i][j] = fmaf(a[i], bb[j], acc[i][j]);
        }
        __syncthreads();
    }
    #pragma unroll
    for (int i = 0; i < 8; i++) {
        int m = m0 + ty * 8 + i;
        float bvv = bm[m];
        #pragma unroll
        for (int j4 = 0; j4 < 8; j4 += 4) {
            float4 r;
            r.x = acc[i][j4 + 0] + bvv; r.y = acc[i][j4 + 1] + bvv;
            r.z = acc[i][j4 + 2] + bvv; r.w = acc[i][j4 + 3] + bvv;
            *(float4*)&outp[(size_t)m * L_DIM + n0 + tx * 8 + j4] = r;
        }
    }
}

// ---------------------------------------------------------------------------
// QKs + M: M[b,l] = max_{s<U} q_l . k_{idx[s]}  -  (sum_{s<U} q_l . k_{idx[s]}) / L
// Block: 64 l-rows x all U samples (s-tiles of 64). 4x4 microtile, fused reduce.
// grid: (L/64=64, B=16), block 256
// ---------------------------------------------------------------------------
__global__ __launch_bounds__(256) void qks_m_kernel(
    const float* __restrict__ q, const float* __restrict__ k,
    const int* __restrict__ idx_sample, float* __restrict__ Mout, int U)
{
    const int b = blockIdx.y;
    const int l0 = blockIdx.x * 64;
    const float* qb = q + (size_t)b * ((size_t)D_DIM * L_DIM);
    const float* kb = k + (size_t)b * ((size_t)D_DIM * L_DIM);

    __shared__ float As[16][68];   // q tile [d][l]
    __shared__ float Bs[16][68];   // k_sample tile [d][s]
    __shared__ int   sidx[64];
    __shared__ float rmax[64][17];
    __shared__ float rsum[64][17];

    const int tid = threadIdx.x;
    const int tx = tid & 15, ty = tid >> 4;

    float runmax[4], runsum[4];
    #pragma unroll
    for (int i = 0; i < 4; i++) { runmax[i] = -__builtin_inff(); runsum[i] = 0.f; }

    const int ntiles = (U + 63) / 64;
    for (int st = 0; st < ntiles; st++) {
        int s0 = st * 64;
        if (tid < 64) {
            int s = s0 + tid;
            sidx[tid] = (s < U) ? idx_sample[s] : 0;
        }
        __syncthreads();
        float acc[4][4];
        #pragma unroll
        for (int i = 0; i < 4; i++)
            #pragma unroll
            for (int j = 0; j < 4; j++) acc[i][j] = 0.f;

        for (int k0 = 0; k0 < D_DIM; k0 += 16) {
            int row = tid >> 2, dq = tid & 3;
            float4 a4 = *(const float4*)&qb[(size_t)(l0 + row) * D_DIM + k0 + dq * 4];
            As[dq * 4 + 0][row] = a4.x; As[dq * 4 + 1][row] = a4.y;
            As[dq * 4 + 2][row] = a4.z; As[dq * 4 + 3][row] = a4.w;
            float4 b4 = *(const float4*)&kb[(size_t)sidx[row] * D_DIM + k0 + dq * 4];
            Bs[dq * 4 + 0][row] = b4.x; Bs[dq * 4 + 1][row] = b4.y;
            Bs[dq * 4 + 2][row] = b4.z; Bs[dq * 4 + 3][row] = b4.w;
            __syncthreads();
            #pragma unroll
            for (int kk = 0; kk < 16; kk++) {
                float a[4], bb[4];
                *(float4*)&a[0]  = *(float4*)&As[kk][ty * 4];
                *(float4*)&bb[0] = *(float4*)&Bs[kk][tx * 4];
                #pragma unroll
                for (int i = 0; i < 4; i++)
                    #pragma unroll
                    for (int j = 0; j < 4; j++)
                        acc[i][j] = fmaf(a[i], bb[j], acc[i][j]);
            }
            __syncthreads();
        }
        #pragma unroll
        for (int i = 0; i < 4; i++)
            #pragma unroll
            for (int j = 0; j < 4; j++) {
                int sg = s0 + tx * 4 + j;
                if (sg < U) {
                    runmax[i] = fmaxf(runmax[i], acc[i][j]);
                    runsum[i] += acc[i][j];
                }
            }
    }
    #pragma unroll
    for (int i = 0; i < 4; i++) {
        rmax[ty * 4 + i][tx] = runmax[i];
        rsum[ty * 4 + i][tx] = runsum[i];
    }
    __syncthreads();
    if (tid < 64) {
        float gm = -__builtin_inff(), gs = 0.f;
        #pragma unroll
        for (int t = 0; t < 16; t++) { gm = fmaxf(gm, rmax[tid][t]); gs += rsum[tid][t]; }
        Mout[(size_t)b * L_DIM + l0 + tid] = gm - gs * (1.f / (float)L_DIM);
    }
}

// ---------------------------------------------------------------------------
// Per-batch top-U selection: full bitonic sort (descending) of 4096 (val,idx)
// pairs in LDS. grid: (B=16), block 512
// ---------------------------------------------------------------------------
__global__ __launch_bounds__(512) void topk_sort(const float* __restrict__ Mv,
                                                 int* __restrict__ topidx, int U)
{
    const int b = blockIdx.x;
    __shared__ float sv[4096];
    __shared__ int   si[4096];
    const int tid = threadIdx.x;
    for (int i = tid; i < 4096; i += 512) { sv[i] = Mv[(size_t)b * 4096 + i]; si[i] = i; }
    __syncthreads();
    for (int kk = 2; kk <= 4096; kk <<= 1) {
        for (int j = kk >> 1; j > 0; j >>= 1) {
            for (int i = tid; i < 4096; i += 512) {
                int ixj = i ^ j;
                if (ixj > i) {
                    bool up = ((i & kk) == 0);   // descending region
                    float vi = sv[i], vj = sv[ixj];
                    bool sw = up ? (vi < vj) : (vi > vj);
                    if (sw) {
                        sv[i] = vj; sv[ixj] = vi;
                        int t = si[i]; si[i] = si[ixj]; si[ixj] = t;
                    }
                }
            }
            __syncthreads();
        }
    }
    for (int r = tid; r < U; r += 512) topidx[b * U + r] = si[r];
}

// ---------------------------------------------------------------------------
// v mean, stage 1: partial sums over 128 l-rows. grid (32, 16), block 512
// ---------------------------------------------------------------------------
__global__ __launch_bounds__(512) void vmean_partial(const float* __restrict__ v,
                                                     float* __restrict__ partial)
{
    const int ch = blockIdx.x, b = blockIdx.y;
    const int d = threadIdx.x;
    const float* vb = v + (size_t)b * ((size_t)D_DIM * L_DIM);
    float acc = 0.f;
    const int lbeg = ch * 128;
    for (int l = lbeg; l < lbeg + 128; l++) acc += vb[(size_t)l * D_DIM + d];
    partial[((size_t)b * 32 + ch) * D_DIM + d] = acc;
}

// stage 2: reduce 32 partials -> vmean. grid (16), block 512
__global__ __launch_bounds__(512) void vmean_reduce(const float* __restrict__ partial,
                                                    float* __restrict__ vmean)
{
    const int b = blockIdx.x;
    const int d = threadIdx.x;
    float acc = 0.f;
    for (int ch = 0; ch < 32; ch++) acc += partial[((size_t)b * 32 + ch) * D_DIM + d];
    vmean[b * D_DIM + d] = acc * (1.f / (float)L_DIM);
}

// Fill all output rows with vmean. grid (B*64=1024), block 256
__global__ __launch_bounds__(256) void fill_out(const float* __restrict__ vmean,
                                                float* __restrict__ out)
{
    const int z = blockIdx.x;
    const int b = z >> 6, lch = z & 63;
    __shared__ float vm[512];
    vm[threadIdx.x] = vmean[b * 512 + threadIdx.x];
    vm[threadIdx.x + 256] = vmean[b * 512 + threadIdx.x + 256];
    __syncthreads();
    float* op = out + (size_t)b * ((size_t)D_DIM * L_DIM) + (size_t)lch * 64 * 512;
    #pragma unroll
    for (int it = 0; it < 32; it++) {
        int flat = (threadIdx.x + it * 256) * 4;
        int d = flat & 511;
        float4 r = { vm[d], vm[d + 1], vm[d + 2], vm[d + 3] };
        *(float4*)&op[flat] = r;
    }
}

// ---------------------------------------------------------------------------
// scores[u,s] = scale * q[topidx[u]] . k[s]   (NT GEMM, gathered A rows)
// grid: (L/64=64, ceil(U/64)=8, B=16), block 256
// ---------------------------------------------------------------------------
__global__ __launch_bounds__(256) void scores_gemm(
    const float* __restrict__ q, const float* __restrict__ k,
    const int* __restrict__ topidx, float* __restrict__ scores, int U)
{
    const int b = blockIdx.z;
    const int s0 = blockIdx.x * 64;
    const int u0 = blockIdx.y * 64;
    const float* qb = q + (size_t)b * ((size_t)D_DIM * L_DIM);
    const float* kb = k + (size_t)b * ((size_t)D_DIM * L_DIM);
    float* sb = scores + (size_t)b * (size_t)U * L_DIM;

    __shared__ float As[16][68];
    __shared__ float Bs[16][68];
    __shared__ int   arow[64];

    const int tid = threadIdx.x;
    const int tx = tid & 15, ty = tid >> 4;

    if (tid < 64) {
        int u = u0 + tid;
        arow[tid] = (u < U) ? topidx[b * U + u] : 0;
    }
    __syncthreads();

    float acc[4][4];
    #pragma unroll
    for (int i = 0; i < 4; i++)
        #pragma unroll
        for (int j = 0; j < 4; j++) acc[i][j] = 0.f;

    for (int k0 = 0; k0 < D_DIM; k0 += 16) {
        int row = tid >> 2, dq = tid & 3;
        float4 a4 = *(const float4*)&qb[(size_t)arow[row] * D_DIM + k0 + dq * 4];
        As[dq * 4 + 0][row] = a4.x; As[dq * 4 + 1][row] = a4.y;
        As[dq * 4 + 2][row] = a4.z; As[dq * 4 + 3][row] = a4.w;
        float4 b4 = *(const float4*)&kb[(size_t)(s0 + row) * D_DIM + k0 + dq * 4];
        Bs[dq * 4 + 0][row] = b4.x; Bs[dq * 4 + 1][row] = b4.y;
        Bs[dq * 4 + 2][row] = b4.z; Bs[dq * 4 + 3][row] = b4.w;
        __syncthreads();
        #pragma unroll
        for (int kk = 0; kk < 16; kk++) {
            float a[4], bb[4];
            *(float4*)&a[0]  = *(float4*)&As[kk][ty * 4];
            *(float4*)&bb[0] = *(float4*)&Bs[kk][tx * 4];
            #pragma unroll
            for (int i = 0; i < 4; i++)
                #pragma unroll
                for (int j = 0; j < 4; j++)
                    acc[i][j] = fmaf(a[i], bb[j], acc[i][j]);
        }
        __syncthreads();
    }
    const float scale = 0.044194173824159216f;  // 1/sqrt(512)
    #pragma unroll
    for (int i = 0; i < 4; i++) {
        int u = u0 + ty * 4 + i;
        if (u < U) {
            float4 r = { acc[i][0] * scale, acc[i][1] * scale,
                         acc[i][2] * scale, acc[i][3] * scale };
            *(float4*)&sb[(size_t)u * L_DIM + s0 + tx * 4] = r;
        }
    }
}

// Row softmax over 4096 entries, in place. grid (B*U=7200), block 256
__global__ __launch_bounds__(256) void softmax_rows(float* __restrict__ scores)
{
    float* row = scores + (size_t)blockIdx.x * L_DIM;
    const int tid = threadIdx.x;
    float x[16];
    #pragma unroll
    for (int t = 0; t < 4; t++) {
        float4 v4 = *(float4*)&row[tid * 4 + t * 1024];
        x[t * 4 + 0] = v4.x; x[t * 4 + 1] = v4.y;
        x[t * 4 + 2] = v4.z; x[t * 4 + 3] = v4.w;
    }
    __shared__ float red[256];
    float lm = -__builtin_inff();
    #pragma unroll
    for (int i = 0; i < 16; i++) lm = fmaxf(lm, x[i]);
    red[tid] = lm;
    __syncthreads();
    for (int o = 128; o > 0; o >>= 1) {
        if (tid < o) red[tid] = fmaxf(red[tid], red[tid + o]);
        __syncthreads();
    }
    float m = red[0];
    __syncthreads();
    float ls = 0.f;
    #pragma unroll
    for (int i = 0; i < 16; i++) { x[i] = expf(x[i] - m); ls += x[i]; }
    red[tid] = ls;
    __syncthreads();
    for (int o = 128; o > 0; o >>= 1) {
        if (tid < o) red[tid] += red[tid + o];
        __syncthreads();
    }
    float inv = 1.f / red[0];
    #pragma unroll
    for (int t = 0; t < 4; t++) {
        float4 v4 = { x[t * 4 + 0] * inv, x[t * 4 + 1] * inv,
                      x[t * 4 + 2] * inv, x[t * 4 + 3] * inv };
        *(float4*)&row[tid * 4 + t * 1024] = v4;
    }
}

// ---------------------------------------------------------------------------
// upd[u,d] = sum_s attn[u,s] * v[s,d]; scatter row -> out[topidx[u]]
// grid: (512/64=8, ceil(U/64)=8, B=16), block 256
// ---------------------------------------------------------------------------
__global__ __launch_bounds__(256) void upd_gemm(
    const float* __restrict__ scores, const float* __restrict__ v,
    const int* __restrict__ topidx, float* __restrict__ out, int U)
{
    const int b = blockIdx.z;
    const int n0 = blockIdx.x * 64;
    const int u0 = blockIdx.y * 64;
    const float* sb = scores + (size_t)b * (size_t)U * L_DIM;
    const float* vb = v + (size_t)b * ((size_t)D_DIM * L_DIM);

    __shared__ float As[16][68];   // attn tile [s][u]
    __shared__ float Bs[16][64];   // v tile    [s][d]

    const int tid = threadIdx.x;
    const int tx = tid & 15, ty = tid >> 4;

    float acc[4][4];
    #pragma unroll
    for (int i = 0; i < 4; i++)
        #pragma unroll
        for (int j = 0; j < 4; j++) acc[i][j] = 0.f;

    for (int k0 = 0; k0 < L_DIM; k0 += 16) {
        {
            int u = tid >> 2, sq = tid & 3;
            int ug = u0 + u;
            int urow = (ug < U) ? ug : 0;
            float4 a4 = *(const float4*)&sb[(size_t)urow * L_DIM + k0 + sq * 4];
            As[sq * 4 + 0][u] = a4.x; As[sq * 4 + 1][u] = a4.y;
            As[sq * 4 + 2][u] = a4.z; As[sq * 4 + 3][u] = a4.w;
            int kk = tid >> 4, nq = tid & 15;
            *(float4*)&Bs[kk][nq * 4] =
                *(const float4*)&vb[(size_t)(k0 + kk) * D_DIM + n0 + nq * 4];
        }
        __syncthreads();
        #pragma unroll
        for (int kk = 0; kk < 16; kk++) {
            float a[4], bb[4];
            *(float4*)&a[0]  = *(float4*)&As[kk][ty * 4];
            *(float4*)&bb[0] = *(float4*)&Bs[kk][tx * 4];
            #pragma unroll
            for (int i = 0; i < 4; i++)
                #pragma unroll
                for (int j = 0; j < 4; j++)
                    acc[i][j] = fmaf(a[i], bb[j], acc[i][j]);
        }
        __syncthreads();
    }
    #pragma unroll
    for (int i = 0; i < 4; i++) {
        int ug = u0 + ty * 4 + i;
        if (ug < U) {
            int lu = topidx[b * U + ug];
            float4 r = { acc[i][0], acc[i][1], acc[i][2], acc[i][3] };
            *(float4*)&out[(size_t)b * ((size_t)D_DIM * L_DIM)
                           + (size_t)lu * D_DIM + n0 + tx * 4] = r;
        }
    }
}

// ---------------------------------------------------------------------------
extern "C" void kernel_launch(void* const* d_in, const int* in_sizes, int n_in,
                              void* d_out, int out_size, void* d_ws, size_t ws_size,
                              hipStream_t stream)
{
    const float* x1 = (const float*)d_in[0];
    const float* x2 = (const float*)d_in[1];
    const float* Wq = (const float*)d_in[2];
    const float* bq = (const float*)d_in[3];
    const float* Wk = (const float*)d_in[4];
    const float* bk = (const float*)d_in[5];
    const float* Wv = (const float*)d_in[6];
    const float* bv = (const float*)d_in[7];
    const int*  idx = (const int*)d_in[8];
    const int U = in_sizes[8];            // 450

    float* out = (float*)d_out;
    float* ws  = (float*)d_ws;

    const size_t perB = (size_t)D_DIM * L_DIM;      // 2,097,152
    float* q      = ws;
    float* k      = q + (size_t)BATCH * perB;
    float* v      = k + (size_t)BATCH * perB;
    float* scores = v + (size_t)BATCH * perB;
    float* Mbuf   = scores + (size_t)BATCH * (size_t)U * L_DIM;
    float* vmean  = Mbuf + (size_t)BATCH * L_DIM;
    float* part   = vmean + (size_t)BATCH * D_DIM;
    int*   topidx = (int*)(part + (size_t)BATCH * 32 * D_DIM);

    // 1. projections q,k,v
    proj_gemm<<<dim3(L_DIM / 128, D_DIM / 128, BATCH * 3), 256, 0, stream>>>(
        x1, x2, Wq, bq, Wk, bk, Wv, bv, q, k, v);

    // 2. v mean + output fill
    vmean_partial<<<dim3(32, BATCH), 512, 0, stream>>>(v, part);
    vmean_reduce<<<BATCH, 512, 0, stream>>>(part, vmean);
    fill_out<<<BATCH * 64, 256, 0, stream>>>(vmean, out);

    // 3. sampled QK^T -> M
    qks_m_kernel<<<dim3(L_DIM / 64, BATCH), 256, 0, stream>>>(q, k, idx, Mbuf, U);

    // 4. top-U per batch
    topk_sort<<<BATCH, 512, 0, stream>>>(Mbuf, topidx, U);

    // 5. full scores for selected rows, softmax, attn @ V scattered into out
    const int utiles = (U + 63) / 64;
    scores_gemm<<<dim3(L_DIM / 64, utiles, BATCH), 256, 0, stream>>>(
        q, k, topidx, scores, U);
    softmax_rows<<<BATCH * U, 256, 0, stream>>>(scores);
    upd_gemm<<<dim3(D_DIM / 64, utiles, BATCH), 256, 0, stream>>>(
        scores, v, topidx, out, U);
}

// Round 2
// 2139.474 us; speedup vs baseline: 1.4070x; 1.4070x over previous
//
#include <hip/hip_runtime.h>
#include <cstdint>
#include <cstddef>

#define L_DIM 4096
#define D_DIM 512
#define C_DIM 512
#define CIN   256
#define BATCH 16

typedef _Float16 half8 __attribute__((ext_vector_type(8)));
typedef float f32x4 __attribute__((ext_vector_type(4)));

__device__ __forceinline__ void gld16(const _Float16* g, _Float16* l) {
    __builtin_amdgcn_global_load_lds(
        (const __attribute__((address_space(1))) unsigned int*)g,
        (__attribute__((address_space(3))) unsigned int*)l,
        16, 0, 0);
}

// ---------------------------------------------------------------------------
// Split W (3 x 512x512 fp32, row-major [o][c]) into fp16 hi/lo.
// grid (1024, 3), block 256
// ---------------------------------------------------------------------------
__global__ __launch_bounds__(256) void convert_w(
    const float* __restrict__ Wq, const float* __restrict__ Wk,
    const float* __restrict__ Wv,
    _Float16* __restrict__ Wh, _Float16* __restrict__ Wl)
{
    const int w = blockIdx.y;
    const float* src = (w == 0) ? Wq : (w == 1) ? Wk : Wv;
    int i = blockIdx.x * 256 + threadIdx.x;
    float xv = src[i];
    _Float16 hi = (_Float16)xv;
    Wh[(size_t)w * 262144 + i] = hi;
    Wl[(size_t)w * 262144 + i] = (_Float16)(xv - (float)hi);
}

// ---------------------------------------------------------------------------
// Transpose + split X: XT[s][c] = concat(x1,x2)[c][s] as fp16 hi/lo.
// Per phase handles 8 batches. grid (64, 8, 8), block 256.
// ---------------------------------------------------------------------------
__global__ __launch_bounds__(256) void convert_x(
    const float* __restrict__ x1, const float* __restrict__ x2,
    _Float16* __restrict__ XTh, _Float16* __restrict__ XTl, int phase)
{
    const int bb = blockIdx.z;
    const int b = phase * 8 + bb;
    const int s0 = blockIdx.x * 64;
    const int c0 = blockIdx.y * 64;
    __shared__ float t[64][65];
    const int tid = threadIdx.x;
    const int g = tid >> 6, sy = tid & 63;
    const float* src = (c0 < CIN)
        ? (x1 + (size_t)b * CIN * L_DIM + (size_t)c0 * L_DIM)
        : (x2 + (size_t)b * CIN * L_DIM + (size_t)(c0 - CIN) * L_DIM);
    #pragma unroll
    for (int r = 0; r < 16; r++) {
        int cl = g * 16 + r;
        t[cl][sy] = src[(size_t)cl * L_DIM + s0 + sy];
    }
    __syncthreads();
    _Float16* outh = XTh + (size_t)bb * L_DIM * 512 + (size_t)s0 * 512 + c0;
    _Float16* outl = XTl + (size_t)bb * L_DIM * 512 + (size_t)s0 * 512 + c0;
    #pragma unroll
    for (int r = 0; r < 16; r++) {
        int sl = g * 16 + r;
        float xv = t[sy][sl];
        _Float16 hi = (_Float16)xv;
        float lo = xv - (float)hi;
        outh[(size_t)sl * 512 + sy] = hi;
        outl[(size_t)sl * 512 + sy] = (_Float16)lo;
    }
}

// ---------------------------------------------------------------------------
// Projection via fp16x3 MFMA: C[o][s] = sum_c W[o][c] X[c][s] + bias[o]
// A = W [o][c] (k-contig), B^T = XT [s][c] (k-contig), C fp32 [o][s].
// 128x128 tile, BK=32, mfma_f32_16x16x32_f16, global_load_lds(16) staging.
// grid: (4096/128=32, 512/128=4, 8*3=24), block 256 (4 waves, 2x2 of 64x64)
// ---------------------------------------------------------------------------
__global__ __launch_bounds__(256) void proj_mfma(
    const _Float16* __restrict__ Wh, const _Float16* __restrict__ Wl,
    const _Float16* __restrict__ XTh, const _Float16* __restrict__ XTl,
    const float* __restrict__ bq, const float* __restrict__ bk,
    const float* __restrict__ bv,
    float* __restrict__ qout, float* __restrict__ kout, float* __restrict__ vout,
    int phase)
{
    const int z = blockIdx.z;
    const int bb = z / 3, w = z % 3;
    const int b = phase * 8 + bb;
    const _Float16* Ah_g = Wh + (size_t)w * 262144;
    const _Float16* Al_g = Wl + (size_t)w * 262144;
    const _Float16* Bh_g = XTh + (size_t)bb * ((size_t)L_DIM * 512);
    const _Float16* Bl_g = XTl + (size_t)bb * ((size_t)L_DIM * 512);
    const float* bias = (w == 0) ? bq : (w == 1) ? bk : bv;
    float* outp = ((w == 0) ? qout : (w == 1) ? kout : vout)
                  + (size_t)b * ((size_t)D_DIM * L_DIM);

    const int m0 = blockIdx.y * 128;
    const int n0 = blockIdx.x * 128;

    __shared__ _Float16 lds[4 * 128 * 32];      // Ah | Al | Bh | Bl, 32 KB
    _Float16* ldsA_h = lds;
    _Float16* ldsA_l = lds + 4096;
    _Float16* ldsB_h = lds + 8192;
    _Float16* ldsB_l = lds + 12288;

    const int tid = threadIdx.x;
    const int w4 = tid >> 6, lane = tid & 63;
    const int lr = lane & 15, quad = lane >> 4;
    const int wr = w4 >> 1, wc = w4 & 1;

    f32x4 acc[4][4] = {};

    // staging: slot q in [0,512) per 8KB array; r=q>>2 (row), c4=q&3 (16B chunk)
    const int q1 = w4 * 128 + lane, q2 = q1 + 64;
    const int r1 = q1 >> 2, c41 = q1 & 3;
    const int r2 = q2 >> 2, c42 = q2 & 3;

    const _Float16* pAh1 = Ah_g + (size_t)(m0 + r1) * 512 + c41 * 8;
    const _Float16* pAh2 = Ah_g + (size_t)(m0 + r2) * 512 + c42 * 8;
    const _Float16* pAl1 = Al_g + (size_t)(m0 + r1) * 512 + c41 * 8;
    const _Float16* pAl2 = Al_g + (size_t)(m0 + r2) * 512 + c42 * 8;
    const _Float16* pBh1 = Bh_g + (size_t)(n0 + r1) * 512 + c41 * 8;
    const _Float16* pBh2 = Bh_g + (size_t)(n0 + r2) * 512 + c42 * 8;
    const _Float16* pBl1 = Bl_g + (size_t)(n0 + r1) * 512 + c41 * 8;
    const _Float16* pBl2 = Bl_g + (size_t)(n0 + r2) * 512 + c42 * 8;

    _Float16* dst1A_h = ldsA_h + (size_t)(w4 * 128) * 8;
    _Float16* dst2A_h = ldsA_h + (size_t)(w4 * 128 + 64) * 8;
    _Float16* dst1A_l = ldsA_l + (size_t)(w4 * 128) * 8;
    _Float16* dst2A_l = ldsA_l + (size_t)(w4 * 128 + 64) * 8;
    _Float16* dst1B_h = ldsB_h + (size_t)(w4 * 128) * 8;
    _Float16* dst2B_h = ldsB_h + (size_t)(w4 * 128 + 64) * 8;
    _Float16* dst1B_l = ldsB_l + (size_t)(w4 * 128) * 8;
    _Float16* dst2B_l = ldsB_l + (size_t)(w4 * 128 + 64) * 8;

    for (int k0 = 0; k0 < 512; k0 += 32) {
        if (k0) __syncthreads();
        gld16(pAh1 + k0, dst1A_h);
        gld16(pAh2 + k0, dst2A_h);
        gld16(pAl1 + k0, dst1A_l);
        gld16(pAl2 + k0, dst2A_l);
        gld16(pBh1 + k0, dst1B_h);
        gld16(pBh2 + k0, dst2B_h);
        gld16(pBl1 + k0, dst1B_l);
        gld16(pBl2 + k0, dst2B_l);
        __syncthreads();

        half8 fAh[4], fAl[4];
        #pragma unroll
        for (int i = 0; i < 4; i++) {
            int m = wr * 64 + i * 16 + lr;
            fAh[i] = *(const half8*)(ldsA_h + m * 32 + quad * 8);
            fAl[i] = *(const half8*)(ldsA_l + m * 32 + quad * 8);
        }
        #pragma unroll
        for (int j = 0; j < 4; j++) {
            int n = wc * 64 + j * 16 + lr;
            half8 fBh = *(const half8*)(ldsB_h + n * 32 + quad * 8);
            half8 fBl = *(const half8*)(ldsB_l + n * 32 + quad * 8);
            #pragma unroll
            for (int i = 0; i < 4; i++) {
                acc[i][j] = __builtin_amdgcn_mfma_f32_16x16x32_f16(fAh[i], fBh, acc[i][j], 0, 0, 0);
                acc[i][j] = __builtin_amdgcn_mfma_f32_16x16x32_f16(fAl[i], fBh, acc[i][j], 0, 0, 0);
                acc[i][j] = __builtin_amdgcn_mfma_f32_16x16x32_f16(fAh[i], fBl, acc[i][j], 0, 0, 0);
            }
        }
    }

    // epilogue: C row m = m0 + wr*64 + i*16 + quad*4 + r ; col n = n0 + wc*64 + j*16 + lr
    #pragma unroll
    for (int i = 0; i < 4; i++) {
        int mg = m0 + wr * 64 + i * 16 + quad * 4;
        #pragma unroll
        for (int r = 0; r < 4; r++) {
            float bvv = bias[mg + r];
            #pragma unroll
            for (int j = 0; j < 4; j++) {
                int ng = n0 + wc * 64 + j * 16 + lr;
                outp[(size_t)(mg + r) * L_DIM + ng] = acc[i][j][r] + bvv;
            }
        }
    }
}

// ---------------------------------------------------------------------------
// QKs + M (unchanged fp32)
// ---------------------------------------------------------------------------
__global__ __launch_bounds__(256) void qks_m_kernel(
    const float* __restrict__ q, const float* __restrict__ k,
    const int* __restrict__ idx_sample, float* __restrict__ Mout, int U)
{
    const int b = blockIdx.y;
    const int l0 = blockIdx.x * 64;
    const float* qb = q + (size_t)b * ((size_t)D_DIM * L_DIM);
    const float* kb = k + (size_t)b * ((size_t)D_DIM * L_DIM);

    __shared__ float As[16][68];
    __shared__ float Bs[16][68];
    __shared__ int   sidx[64];
    __shared__ float rmax[64][17];
    __shared__ float rsum[64][17];

    const int tid = threadIdx.x;
    const int tx = tid & 15, ty = tid >> 4;

    float runmax[4], runsum[4];
    #pragma unroll
    for (int i = 0; i < 4; i++) { runmax[i] = -__builtin_inff(); runsum[i] = 0.f; }

    const int ntiles = (U + 63) / 64;
    for (int st = 0; st < ntiles; st++) {
        int s0 = st * 64;
        if (tid < 64) {
            int s = s0 + tid;
            sidx[tid] = (s < U) ? idx_sample[s] : 0;
        }
        __syncthreads();
        float acc[4][4];
        #pragma unroll
        for (int i = 0; i < 4; i++)
            #pragma unroll
            for (int j = 0; j < 4; j++) acc[i][j] = 0.f;

        for (int k0 = 0; k0 < D_DIM; k0 += 16) {
            int row = tid >> 2, dq = tid & 3;
            float4 a4 = *(const float4*)&qb[(size_t)(l0 + row) * D_DIM + k0 + dq * 4];
            As[dq * 4 + 0][row] = a4.x; As[dq * 4 + 1][row] = a4.y;
            As[dq * 4 + 2][row] = a4.z; As[dq * 4 + 3][row] = a4.w;
            float4 b4 = *(const float4*)&kb[(size_t)sidx[row] * D_DIM + k0 + dq * 4];
            Bs[dq * 4 + 0][row] = b4.x; Bs[dq * 4 + 1][row] = b4.y;
            Bs[dq * 4 + 2][row] = b4.z; Bs[dq * 4 + 3][row] = b4.w;
            __syncthreads();
            #pragma unroll
            for (int kk = 0; kk < 16; kk++) {
                float a[4], bb[4];
                *(float4*)&a[0]  = *(float4*)&As[kk][ty * 4];
                *(float4*)&bb[0] = *(float4*)&Bs[kk][tx * 4];
                #pragma unroll
                for (int i = 0; i < 4; i++)
                    #pragma unroll
                    for (int j = 0; j < 4; j++)
                        acc[i][j] = fmaf(a[i], bb[j], acc[i][j]);
            }
            __syncthreads();
        }
        #pragma unroll
        for (int i = 0; i < 4; i++)
            #pragma unroll
            for (int j = 0; j < 4; j++) {
                int sg = s0 + tx * 4 + j;
                if (sg < U) {
                    runmax[i] = fmaxf(runmax[i], acc[i][j]);
                    runsum[i] += acc[i][j];
                }
            }
    }
    #pragma unroll
    for (int i = 0; i < 4; i++) {
        rmax[ty * 4 + i][tx] = runmax[i];
        rsum[ty * 4 + i][tx] = runsum[i];
    }
    __syncthreads();
    if (tid < 64) {
        float gm = -__builtin_inff(), gs = 0.f;
        #pragma unroll
        for (int t = 0; t < 16; t++) { gm = fmaxf(gm, rmax[tid][t]); gs += rsum[tid][t]; }
        Mout[(size_t)b * L_DIM + l0 + tid] = gm - gs * (1.f / (float)L_DIM);
    }
}

// ---------------------------------------------------------------------------
// Per-batch top-U: bitonic sort in LDS (unchanged)
// ---------------------------------------------------------------------------
__global__ __launch_bounds__(512) void topk_sort(const float* __restrict__ Mv,
                                                 int* __restrict__ topidx, int U)
{
    const int b = blockIdx.x;
    __shared__ float sv[4096];
    __shared__ int   si[4096];
    const int tid = threadIdx.x;
    for (int i = tid; i < 4096; i += 512) { sv[i] = Mv[(size_t)b * 4096 + i]; si[i] = i; }
    __syncthreads();
    for (int kk = 2; kk <= 4096; kk <<= 1) {
        for (int j = kk >> 1; j > 0; j >>= 1) {
            for (int i = tid; i < 4096; i += 512) {
                int ixj = i ^ j;
                if (ixj > i) {
                    bool up = ((i & kk) == 0);
                    float vi = sv[i], vj = sv[ixj];
                    bool sw = up ? (vi < vj) : (vi > vj);
                    if (sw) {
                        sv[i] = vj; sv[ixj] = vi;
                        int t = si[i]; si[i] = si[ixj]; si[ixj] = t;
                    }
                }
            }
            __syncthreads();
        }
    }
    for (int r = tid; r < U; r += 512) topidx[b * U + r] = si[r];
}

// ---------------------------------------------------------------------------
__global__ __launch_bounds__(512) void vmean_partial(const float* __restrict__ v,
                                                     float* __restrict__ partial)
{
    const int ch = blockIdx.x, b = blockIdx.y;
    const int d = threadIdx.x;
    const float* vb = v + (size_t)b * ((size_t)D_DIM * L_DIM);
    float acc = 0.f;
    const int lbeg = ch * 128;
    for (int l = lbeg; l < lbeg + 128; l++) acc += vb[(size_t)l * D_DIM + d];
    partial[((size_t)b * 32 + ch) * D_DIM + d] = acc;
}

__global__ __launch_bounds__(512) void vmean_reduce(const float* __restrict__ partial,
                                                    float* __restrict__ vmean)
{
    const int b = blockIdx.x;
    const int d = threadIdx.x;
    float acc = 0.f;
    for (int ch = 0; ch < 32; ch++) acc += partial[((size_t)b * 32 + ch) * D_DIM + d];
    vmean[b * D_DIM + d] = acc * (1.f / (float)L_DIM);
}

__global__ __launch_bounds__(256) void fill_out(const float* __restrict__ vmean,
                                                float* __restrict__ out)
{
    const int z = blockIdx.x;
    const int b = z >> 6, lch = z & 63;
    __shared__ float vm[512];
    vm[threadIdx.x] = vmean[b * 512 + threadIdx.x];
    vm[threadIdx.x + 256] = vmean[b * 512 + threadIdx.x + 256];
    __syncthreads();
    float* op = out + (size_t)b * ((size_t)D_DIM * L_DIM) + (size_t)lch * 64 * 512;
    #pragma unroll
    for (int it = 0; it < 32; it++) {
        int flat = (threadIdx.x + it * 256) * 4;
        int d = flat & 511;
        float4 r = { vm[d], vm[d + 1], vm[d + 2], vm[d + 3] };
        *(float4*)&op[flat] = r;
    }
}

// ---------------------------------------------------------------------------
// scores (unchanged fp32)
// ---------------------------------------------------------------------------
__global__ __launch_bounds__(256) void scores_gemm(
    const float* __restrict__ q, const float* __restrict__ k,
    const int* __restrict__ topidx, float* __restrict__ scores, int U)
{
    const int b = blockIdx.z;
    const int s0 = blockIdx.x * 64;
    const int u0 = blockIdx.y * 64;
    const float* qb = q + (size_t)b * ((size_t)D_DIM * L_DIM);
    const float* kb = k + (size_t)b * ((size_t)D_DIM * L_DIM);
    float* sb = scores + (size_t)b * (size_t)U * L_DIM;

    __shared__ float As[16][68];
    __shared__ float Bs[16][68];
    __shared__ int   arow[64];

    const int tid = threadIdx.x;
    const int tx = tid & 15, ty = tid >> 4;

    if (tid < 64) {
        int u = u0 + tid;
        arow[tid] = (u < U) ? topidx[b * U + u] : 0;
    }
    __syncthreads();

    float acc[4][4];
    #pragma unroll
    for (int i = 0; i < 4; i++)
        #pragma unroll
        for (int j = 0; j < 4; j++) acc[i][j] = 0.f;

    for (int k0 = 0; k0 < D_DIM; k0 += 16) {
        int row = tid >> 2, dq = tid & 3;
        float4 a4 = *(const float4*)&qb[(size_t)arow[row] * D_DIM + k0 + dq * 4];
        As[dq * 4 + 0][row] = a4.x; As[dq * 4 + 1][row] = a4.y;
        As[dq * 4 + 2][row] = a4.z; As[dq * 4 + 3][row] = a4.w;
        float4 b4 = *(const float4*)&kb[(size_t)(s0 + row) * D_DIM + k0 + dq * 4];
        Bs[dq * 4 + 0][row] = b4.x; Bs[dq * 4 + 1][row] = b4.y;
        Bs[dq * 4 + 2][row] = b4.z; Bs[dq * 4 + 3][row] = b4.w;
        __syncthreads();
        #pragma unroll
        for (int kk = 0; kk < 16; kk++) {
            float a[4], bb[4];
            *(float4*)&a[0]  = *(float4*)&As[kk][ty * 4];
            *(float4*)&bb[0] = *(float4*)&Bs[kk][tx * 4];
            #pragma unroll
            for (int i = 0; i < 4; i++)
                #pragma unroll
                for (int j = 0; j < 4; j++)
                    acc[i][j] = fmaf(a[i], bb[j], acc[i][j]);
        }
        __syncthreads();
    }
    const float scale = 0.044194173824159216f;
    #pragma unroll
    for (int i = 0; i < 4; i++) {
        int u = u0 + ty * 4 + i;
        if (u < U) {
            float4 r = { acc[i][0] * scale, acc[i][1] * scale,
                         acc[i][2] * scale, acc[i][3] * scale };
            *(float4*)&sb[(size_t)u * L_DIM + s0 + tx * 4] = r;
        }
    }
}

__global__ __launch_bounds__(256) void softmax_rows(float* __restrict__ scores)
{
    float* row = scores + (size_t)blockIdx.x * L_DIM;
    const int tid = threadIdx.x;
    float x[16];
    #pragma unroll
    for (int t = 0; t < 4; t++) {
        float4 v4 = *(float4*)&row[tid * 4 + t * 1024];
        x[t * 4 + 0] = v4.x; x[t * 4 + 1] = v4.y;
        x[t * 4 + 2] = v4.z; x[t * 4 + 3] = v4.w;
    }
    __shared__ float red[256];
    float lm = -__builtin_inff();
    #pragma unroll
    for (int i = 0; i < 16; i++) lm = fmaxf(lm, x[i]);
    red[tid] = lm;
    __syncthreads();
    for (int o = 128; o > 0; o >>= 1) {
        if (tid < o) red[tid] = fmaxf(red[tid], red[tid + o]);
        __syncthreads();
    }
    float m = red[0];
    __syncthreads();
    float ls = 0.f;
    #pragma unroll
    for (int i = 0; i < 16; i++) { x[i] = expf(x[i] - m); ls += x[i]; }
    red[tid] = ls;
    __syncthreads();
    for (int o = 128; o > 0; o >>= 1) {
        if (tid < o) red[tid] += red[tid + o];
        __syncthreads();
    }
    float inv = 1.f / red[0];
    #pragma unroll
    for (int t = 0; t < 4; t++) {
        float4 v4 = { x[t * 4 + 0] * inv, x[t * 4 + 1] * inv,
                      x[t * 4 + 2] * inv, x[t * 4 + 3] * inv };
        *(float4*)&row[tid * 4 + t * 1024] = v4;
    }
}

// ---------------------------------------------------------------------------
// upd (unchanged fp32)
// ---------------------------------------------------------------------------
__global__ __launch_bounds__(256) void upd_gemm(
    const float* __restrict__ scores, const float* __restrict__ v,
    const int* __restrict__ topidx, float* __restrict__ out, int U)
{
    const int b = blockIdx.z;
    const int n0 = blockIdx.x * 64;
    const int u0 = blockIdx.y * 64;
    const float* sb = scores + (size_t)b * (size_t)U * L_DIM;
    const float* vb = v + (size_t)b * ((size_t)D_DIM * L_DIM);

    __shared__ float As[16][68];
    __shared__ float Bs[16][64];

    const int tid = threadIdx.x;
    const int tx = tid & 15, ty = tid >> 4;

    float acc[4][4];
    #pragma unroll
    for (int i = 0; i < 4; i++)
        #pragma unroll
        for (int j = 0; j < 4; j++) acc[i][j] = 0.f;

    for (int k0 = 0; k0 < L_DIM; k0 += 16) {
        {
            int u = tid >> 2, sq = tid & 3;
            int ug = u0 + u;
            int urow = (ug < U) ? ug : 0;
            float4 a4 = *(const float4*)&sb[(size_t)urow * L_DIM + k0 + sq * 4];
            As[sq * 4 + 0][u] = a4.x; As[sq * 4 + 1][u] = a4.y;
            As[sq * 4 + 2][u] = a4.z; As[sq * 4 + 3][u] = a4.w;
            int kk = tid >> 4, nq = tid & 15;
            *(float4*)&Bs[kk][nq * 4] =
                *(const float4*)&vb[(size_t)(k0 + kk) * D_DIM + n0 + nq * 4];
        }
        __syncthreads();
        #pragma unroll
        for (int kk = 0; kk < 16; kk++) {
            float a[4], bb[4];
            *(float4*)&a[0]  = *(float4*)&As[kk][ty * 4];
            *(float4*)&bb[0] = *(float4*)&Bs[kk][tx * 4];
            #pragma unroll
            for (int i = 0; i < 4; i++)
                #pragma unroll
                for (int j = 0; j < 4; j++)
                    acc[i][j] = fmaf(a[i], bb[j], acc[i][j]);
        }
        __syncthreads();
    }
    #pragma unroll
    for (int i = 0; i < 4; i++) {
        int ug = u0 + ty * 4 + i;
        if (ug < U) {
            int lu = topidx[b * U + ug];
            float4 r = { acc[i][0], acc[i][1], acc[i][2], acc[i][3] };
            *(float4*)&out[(size_t)b * ((size_t)D_DIM * L_DIM)
                           + (size_t)lu * D_DIM + n0 + tx * 4] = r;
        }
    }
}

// ---------------------------------------------------------------------------
extern "C" void kernel_launch(void* const* d_in, const int* in_sizes, int n_in,
                              void* d_out, int out_size, void* d_ws, size_t ws_size,
                              hipStream_t stream)
{
    const float* x1 = (const float*)d_in[0];
    const float* x2 = (const float*)d_in[1];
    const float* Wq = (const float*)d_in[2];
    const float* bq = (const float*)d_in[3];
    const float* Wk = (const float*)d_in[4];
    const float* bk = (const float*)d_in[5];
    const float* Wv = (const float*)d_in[6];
    const float* bv = (const float*)d_in[7];
    const int*  idx = (const int*)d_in[8];
    const int U = in_sizes[8];            // 450

    float* out = (float*)d_out;
    float* ws  = (float*)d_ws;

    const size_t perB = (size_t)D_DIM * L_DIM;      // 2,097,152 floats
    float* q = ws;
    float* k = q + (size_t)BATCH * perB;
    float* v = k + (size_t)BATCH * perB;
    float* S = v + (size_t)BATCH * perB;            // union region (118 MB)

    // phase-scoped aliases inside S (alive only until proj done):
    _Float16* XTh = (_Float16*)S;                   // 8 batches * 4096*512 halves
    _Float16* XTl = XTh + (size_t)8 * L_DIM * 512;
    _Float16* Wh  = XTl + (size_t)8 * L_DIM * 512;
    _Float16* Wl  = Wh + (size_t)3 * 512 * 512;     // ends at 70.25 MB < 118 MB

    float* scores = S;                              // after proj
    float* Mbuf   = S + (size_t)BATCH * (size_t)U * L_DIM;
    float* vmean  = Mbuf + (size_t)BATCH * L_DIM;
    float* part   = vmean + (size_t)BATCH * D_DIM;
    int*   topidx = (int*)(part + (size_t)BATCH * 32 * D_DIM);

    // 1. split W once
    convert_w<<<dim3(1024, 3), 256, 0, stream>>>(Wq, Wk, Wv, Wh, Wl);

    // 2. projections in two 8-batch phases (XT aliases the scores region)
    for (int phase = 0; phase < 2; phase++) {
        convert_x<<<dim3(64, 8, 8), 256, 0, stream>>>(x1, x2, XTh, XTl, phase);
        proj_mfma<<<dim3(L_DIM / 128, D_DIM / 128, 8 * 3), 256, 0, stream>>>(
            Wh, Wl, XTh, XTl, bq, bk, bv, q, k, v, phase);
    }

    // 3. v mean + output fill
    vmean_partial<<<dim3(32, BATCH), 512, 0, stream>>>(v, part);
    vmean_reduce<<<BATCH, 512, 0, stream>>>(part, vmean);
    fill_out<<<BATCH * 64, 256, 0, stream>>>(vmean, out);

    // 4. sampled QK^T -> M
    qks_m_kernel<<<dim3(L_DIM / 64, BATCH), 256, 0, stream>>>(q, k, idx, Mbuf, U);

    // 5. top-U per batch
    topk_sort<<<BATCH, 512, 0, stream>>>(Mbuf, topidx, U);

    // 6. scores, softmax, attn @ V scattered into out
    const int utiles = (U + 63) / 64;
    scores_gemm<<<dim3(L_DIM / 64, utiles, BATCH), 256, 0, stream>>>(
        q, k, topidx, scores, U);
    softmax_rows<<<BATCH * U, 256, 0, stream>>>(scores);
    upd_gemm<<<dim3(D_DIM / 64, utiles, BATCH), 256, 0, stream>>>(
        scores, v, topidx, out, U);
}

// Round 3
// 1231.263 us; speedup vs baseline: 2.4448x; 1.7376x over previous
//
#include <hip/hip_runtime.h>
#include <cstdint>
#include <cstddef>

#define L_DIM 4096
#define D_DIM 512
#define CIN   256
#define BATCH 16

typedef _Float16 half8 __attribute__((ext_vector_type(8)));
typedef unsigned short ushort8 __attribute__((ext_vector_type(8)));
typedef float f32x4 __attribute__((ext_vector_type(4)));

__device__ __forceinline__ void gld16(const _Float16* g, _Float16* l) {
    __builtin_amdgcn_global_load_lds(
        (const __attribute__((address_space(1))) unsigned int*)g,
        (__attribute__((address_space(3))) unsigned int*)l,
        16, 0, 0);
}

// ---------------------------------------------------------------------------
// Split W (3 x 512x512 fp32) into fp16 hi/lo. grid (1024,3), block 256
// ---------------------------------------------------------------------------
__global__ __launch_bounds__(256) void convert_w(
    const float* __restrict__ Wq, const float* __restrict__ Wk,
    const float* __restrict__ Wv,
    _Float16* __restrict__ Wh, _Float16* __restrict__ Wl)
{
    const int w = blockIdx.y;
    const float* src = (w == 0) ? Wq : (w == 1) ? Wk : Wv;
    int i = blockIdx.x * 256 + threadIdx.x;
    float xv = src[i];
    _Float16 hi = (_Float16)xv;
    Wh[(size_t)w * 262144 + i] = hi;
    Wl[(size_t)w * 262144 + i] = (_Float16)(xv - (float)hi);
}

// ---------------------------------------------------------------------------
// Transpose + split X. Per phase 8 batches. grid (64, 8, 8), block 256.
// ---------------------------------------------------------------------------
__global__ __launch_bounds__(256) void convert_x(
    const float* __restrict__ x1, const float* __restrict__ x2,
    _Float16* __restrict__ XTh, _Float16* __restrict__ XTl, int phase)
{
    const int bb = blockIdx.z;
    const int b = phase * 8 + bb;
    const int s0 = blockIdx.x * 64;
    const int c0 = blockIdx.y * 64;
    __shared__ float t[64][65];
    const int tid = threadIdx.x;
    const int g = tid >> 6, sy = tid & 63;
    const float* src = (c0 < CIN)
        ? (x1 + (size_t)b * CIN * L_DIM + (size_t)c0 * L_DIM)
        : (x2 + (size_t)b * CIN * L_DIM + (size_t)(c0 - CIN) * L_DIM);
    #pragma unroll
    for (int r = 0; r < 16; r++) {
        int cl = g * 16 + r;
        t[cl][sy] = src[(size_t)cl * L_DIM + s0 + sy];
    }
    __syncthreads();
    _Float16* outh = XTh + (size_t)bb * L_DIM * 512 + (size_t)s0 * 512 + c0;
    _Float16* outl = XTl + (size_t)bb * L_DIM * 512 + (size_t)s0 * 512 + c0;
    #pragma unroll
    for (int r = 0; r < 16; r++) {
        int sl = g * 16 + r;
        float xv = t[sy][sl];
        _Float16 hi = (_Float16)xv;
        float lo = xv - (float)hi;
        outh[(size_t)sl * 512 + sy] = hi;
        outl[(size_t)sl * 512 + sy] = (_Float16)lo;
    }
}

// ---------------------------------------------------------------------------
// Projection via fp16x3 MFMA, epilogue writes hi/lo fp16 pairs.
// grid: (32, 4, 24), block 256
// ---------------------------------------------------------------------------
__global__ __launch_bounds__(256) void proj_mfma(
    const _Float16* __restrict__ Wh, const _Float16* __restrict__ Wl,
    const _Float16* __restrict__ XTh, const _Float16* __restrict__ XTl,
    const float* __restrict__ bq, const float* __restrict__ bk,
    const float* __restrict__ bv,
    _Float16* __restrict__ qh, _Float16* __restrict__ ql,
    _Float16* __restrict__ kh, _Float16* __restrict__ kl,
    _Float16* __restrict__ vh, _Float16* __restrict__ vl,
    int phase)
{
    const int z = blockIdx.z;
    const int bb = z / 3, w = z % 3;
    const int b = phase * 8 + bb;
    const _Float16* Ah_g = Wh + (size_t)w * 262144;
    const _Float16* Al_g = Wl + (size_t)w * 262144;
    const _Float16* Bh_g = XTh + (size_t)bb * ((size_t)L_DIM * 512);
    const _Float16* Bl_g = XTl + (size_t)bb * ((size_t)L_DIM * 512);
    const float* bias = (w == 0) ? bq : (w == 1) ? bk : bv;
    _Float16* outh = ((w == 0) ? qh : (w == 1) ? kh : vh) + (size_t)b * ((size_t)D_DIM * L_DIM);
    _Float16* outl = ((w == 0) ? ql : (w == 1) ? kl : vl) + (size_t)b * ((size_t)D_DIM * L_DIM);

    const int m0 = blockIdx.y * 128;
    const int n0 = blockIdx.x * 128;

    __shared__ _Float16 lds[4 * 128 * 32];
    _Float16* ldsA_h = lds;
    _Float16* ldsA_l = lds + 4096;
    _Float16* ldsB_h = lds + 8192;
    _Float16* ldsB_l = lds + 12288;

    const int tid = threadIdx.x;
    const int w4 = tid >> 6, lane = tid & 63;
    const int lr = lane & 15, quad = lane >> 4;
    const int wr = w4 >> 1, wc = w4 & 1;

    f32x4 acc[4][4] = {};

    const int q1 = w4 * 128 + lane, q2 = q1 + 64;
    const int r1 = q1 >> 2, c41 = q1 & 3;
    const int r2 = q2 >> 2, c42 = q2 & 3;

    const _Float16* pAh1 = Ah_g + (size_t)(m0 + r1) * 512 + c41 * 8;
    const _Float16* pAh2 = Ah_g + (size_t)(m0 + r2) * 512 + c42 * 8;
    const _Float16* pAl1 = Al_g + (size_t)(m0 + r1) * 512 + c41 * 8;
    const _Float16* pAl2 = Al_g + (size_t)(m0 + r2) * 512 + c42 * 8;
    const _Float16* pBh1 = Bh_g + (size_t)(n0 + r1) * 512 + c41 * 8;
    const _Float16* pBh2 = Bh_g + (size_t)(n0 + r2) * 512 + c42 * 8;
    const _Float16* pBl1 = Bl_g + (size_t)(n0 + r1) * 512 + c41 * 8;
    const _Float16* pBl2 = Bl_g + (size_t)(n0 + r2) * 512 + c42 * 8;

    _Float16* d1 = (_Float16*)(lds) + (size_t)(w4 * 128) * 8;
    _Float16* d2 = (_Float16*)(lds) + (size_t)(w4 * 128 + 64) * 8;

    for (int k0 = 0; k0 < 512; k0 += 32) {
        if (k0) __syncthreads();
        gld16(pAh1 + k0, d1);
        gld16(pAh2 + k0, d2);
        gld16(pAl1 + k0, d1 + 4096);
        gld16(pAl2 + k0, d2 + 4096);
        gld16(pBh1 + k0, d1 + 8192);
        gld16(pBh2 + k0, d2 + 8192);
        gld16(pBl1 + k0, d1 + 12288);
        gld16(pBl2 + k0, d2 + 12288);
        __syncthreads();

        half8 fAh[4], fAl[4];
        #pragma unroll
        for (int i = 0; i < 4; i++) {
            int m = wr * 64 + i * 16 + lr;
            fAh[i] = *(const half8*)(ldsA_h + m * 32 + quad * 8);
            fAl[i] = *(const half8*)(ldsA_l + m * 32 + quad * 8);
        }
        #pragma unroll
        for (int j = 0; j < 4; j++) {
            int n = wc * 64 + j * 16 + lr;
            half8 fBh = *(const half8*)(ldsB_h + n * 32 + quad * 8);
            half8 fBl = *(const half8*)(ldsB_l + n * 32 + quad * 8);
            #pragma unroll
            for (int i = 0; i < 4; i++) {
                acc[i][j] = __builtin_amdgcn_mfma_f32_16x16x32_f16(fAh[i], fBh, acc[i][j], 0, 0, 0);
                acc[i][j] = __builtin_amdgcn_mfma_f32_16x16x32_f16(fAl[i], fBh, acc[i][j], 0, 0, 0);
                acc[i][j] = __builtin_amdgcn_mfma_f32_16x16x32_f16(fAh[i], fBl, acc[i][j], 0, 0, 0);
            }
        }
    }

    #pragma unroll
    for (int i = 0; i < 4; i++) {
        int mg = m0 + wr * 64 + i * 16 + quad * 4;
        #pragma unroll
        for (int r = 0; r < 4; r++) {
            float bvv = bias[mg + r];
            #pragma unroll
            for (int j = 0; j < 4; j++) {
                int ng = n0 + wc * 64 + j * 16 + lr;
                float val = acc[i][j][r] + bvv;
                _Float16 hi = (_Float16)val;
                size_t off = (size_t)(mg + r) * L_DIM + ng;
                outh[off] = hi;
                outl[off] = (_Float16)(val - (float)hi);
            }
        }
    }
}

// ---------------------------------------------------------------------------
// qks via fp16x3 MFMA with fused M-reduction.
// C[s][l] = k[idx_s] . q_l ; M[l] = max_s C - sum_s C / L  (s < U)
// grid: (32 l-tiles, 16 b), block 256. A = gathered k rows, B = q rows.
// ---------------------------------------------------------------------------
__global__ __launch_bounds__(256) void qks_mfma(
    const _Float16* __restrict__ qh, const _Float16* __restrict__ ql,
    const _Float16* __restrict__ kh, const _Float16* __restrict__ kl,
    const int* __restrict__ idx_sample, float* __restrict__ Mout, int U)
{
    const int b = blockIdx.y;
    const int l0 = blockIdx.x * 128;
    const size_t perB = (size_t)D_DIM * L_DIM;
    const _Float16* qh_b = qh + (size_t)b * perB;
    const _Float16* ql_b = ql + (size_t)b * perB;
    const _Float16* kh_b = kh + (size_t)b * perB;
    const _Float16* kl_b = kl + (size_t)b * perB;

    __shared__ _Float16 ldsAh[4096], ldsAl[4096];   // gathered k [s][32]
    __shared__ _Float16 ldsBh[4096], ldsBl[4096];   // q [l][32]
    __shared__ int sidx[128];
    __shared__ float redm[8][128];
    __shared__ float reds[8][128];

    const int tid = threadIdx.x;
    const int w4 = tid >> 6, lane = tid & 63;
    const int lr = lane & 15, quad = lane >> 4;
    const int ws = w4 >> 1, wl = w4 & 1;

    float runmax[4], runsum[4];
    #pragma unroll
    for (int j = 0; j < 4; j++) { runmax[j] = -__builtin_inff(); runsum[j] = 0.f; }

    const int ntile = (U + 127) / 128;
    for (int stile = 0; stile < ntile; stile++) {
        const int s0 = stile * 128;
        if (tid < 128) {
            int s = s0 + tid;
            sidx[tid] = (s < U) ? idx_sample[s] : idx_sample[0];
        }
        __syncthreads();

        f32x4 acc[4][4] = {};

        for (int k0 = 0; k0 < 512; k0 += 32) {
            #pragma unroll
            for (int t = 0; t < 2; t++) {
                int c = w4 * 128 + t * 64 + lane;
                int row = c >> 2, part = c & 3;
                int krow = sidx[row];
                _Float16* dst = (_Float16*)0;
                size_t go = (size_t)krow * 512 + k0 + part * 8;
                size_t qo = (size_t)(l0 + row) * 512 + k0 + part * 8;
                int base = (w4 * 128 + t * 64) * 8;
                gld16(kh_b + go, ldsAh + base);
                gld16(kl_b + go, ldsAl + base);
                gld16(qh_b + qo, ldsBh + base);
                gld16(ql_b + qo, ldsBl + base);
                (void)dst;
            }
            __syncthreads();

            half8 fAh[4], fAl[4];
            #pragma unroll
            for (int i = 0; i < 4; i++) {
                int s = ws * 64 + i * 16 + lr;
                fAh[i] = *(const half8*)(ldsAh + s * 32 + quad * 8);
                fAl[i] = *(const half8*)(ldsAl + s * 32 + quad * 8);
            }
            #pragma unroll
            for (int j = 0; j < 4; j++) {
                int l = wl * 64 + j * 16 + lr;
                half8 fBh = *(const half8*)(ldsBh + l * 32 + quad * 8);
                half8 fBl = *(const half8*)(ldsBl + l * 32 + quad * 8);
                #pragma unroll
                for (int i = 0; i < 4; i++) {
                    acc[i][j] = __builtin_amdgcn_mfma_f32_16x16x32_f16(fAh[i], fBh, acc[i][j], 0, 0, 0);
                    acc[i][j] = __builtin_amdgcn_mfma_f32_16x16x32_f16(fAl[i], fBh, acc[i][j], 0, 0, 0);
                    acc[i][j] = __builtin_amdgcn_mfma_f32_16x16x32_f16(fAh[i], fBl, acc[i][j], 0, 0, 0);
                }
            }
            __syncthreads();
        }

        #pragma unroll
        for (int i = 0; i < 4; i++) {
            #pragma unroll
            for (int r = 0; r < 4; r++) {
                int sg = s0 + ws * 64 + i * 16 + quad * 4 + r;
                if (sg < U) {
                    #pragma unroll
                    for (int j = 0; j < 4; j++) {
                        runmax[j] = fmaxf(runmax[j], acc[i][j][r]);
                        runsum[j] += acc[i][j][r];
                    }
                }
            }
        }
        __syncthreads();
    }

    #pragma unroll
    for (int j = 0; j < 4; j++) {
        int l = wl * 64 + j * 16 + lr;
        redm[ws * 4 + quad][l] = runmax[j];
        reds[ws * 4 + quad][l] = runsum[j];
    }
    __syncthreads();
    if (tid < 128) {
        float gm = -__builtin_inff(), gs = 0.f;
        #pragma unroll
        for (int t = 0; t < 8; t++) { gm = fmaxf(gm, redm[t][tid]); gs += reds[t][tid]; }
        Mout[(size_t)b * L_DIM + l0 + tid] = gm - gs * (1.f / (float)L_DIM);
    }
}

// ---------------------------------------------------------------------------
// Per-batch top-U: bitonic sort in LDS (unchanged)
// ---------------------------------------------------------------------------
__global__ __launch_bounds__(512) void topk_sort(const float* __restrict__ Mv,
                                                 int* __restrict__ topidx, int U)
{
    const int b = blockIdx.x;
    __shared__ float sv[4096];
    __shared__ int   si[4096];
    const int tid = threadIdx.x;
    for (int i = tid; i < 4096; i += 512) { sv[i] = Mv[(size_t)b * 4096 + i]; si[i] = i; }
    __syncthreads();
    for (int kk = 2; kk <= 4096; kk <<= 1) {
        for (int j = kk >> 1; j > 0; j >>= 1) {
            for (int i = tid; i < 4096; i += 512) {
                int ixj = i ^ j;
                if (ixj > i) {
                    bool up = ((i & kk) == 0);
                    float vi = sv[i], vj = sv[ixj];
                    bool sw = up ? (vi < vj) : (vi > vj);
                    if (sw) {
                        sv[i] = vj; sv[ixj] = vi;
                        int t = si[i]; si[i] = si[ixj]; si[ixj] = t;
                    }
                }
            }
            __syncthreads();
        }
    }
    for (int r = tid; r < U; r += 512) topidx[b * U + r] = si[r];
}

// ---------------------------------------------------------------------------
// v mean from hi/lo halves
// ---------------------------------------------------------------------------
__global__ __launch_bounds__(512) void vmean_partial(
    const _Float16* __restrict__ vh, const _Float16* __restrict__ vl,
    float* __restrict__ partial)
{
    const int ch = blockIdx.x, b = blockIdx.y;
    const int d = threadIdx.x;
    const _Float16* vhb = vh + (size_t)b * ((size_t)D_DIM * L_DIM);
    const _Float16* vlb = vl + (size_t)b * ((size_t)D_DIM * L_DIM);
    float acc = 0.f;
    const int lbeg = ch * 128;
    for (int l = lbeg; l < lbeg + 128; l++)
        acc += (float)vhb[(size_t)l * D_DIM + d] + (float)vlb[(size_t)l * D_DIM + d];
    partial[((size_t)b * 32 + ch) * D_DIM + d] = acc;
}

__global__ __launch_bounds__(512) void vmean_reduce(const float* __restrict__ partial,
                                                    float* __restrict__ vmean)
{
    const int b = blockIdx.x;
    const int d = threadIdx.x;
    float acc = 0.f;
    for (int ch = 0; ch < 32; ch++) acc += partial[((size_t)b * 32 + ch) * D_DIM + d];
    vmean[b * D_DIM + d] = acc * (1.f / (float)L_DIM);
}

__global__ __launch_bounds__(256) void fill_out(const float* __restrict__ vmean,
                                                float* __restrict__ out)
{
    const int z = blockIdx.x;
    const int b = z >> 6, lch = z & 63;
    __shared__ float vm[512];
    vm[threadIdx.x] = vmean[b * 512 + threadIdx.x];
    vm[threadIdx.x + 256] = vmean[b * 512 + threadIdx.x + 256];
    __syncthreads();
    float* op = out + (size_t)b * ((size_t)D_DIM * L_DIM) + (size_t)lch * 64 * 512;
    #pragma unroll
    for (int it = 0; it < 32; it++) {
        int flat = (threadIdx.x + it * 256) * 4;
        int d = flat & 511;
        float4 r = { vm[d], vm[d + 1], vm[d + 2], vm[d + 3] };
        *(float4*)&op[flat] = r;
    }
}

// ---------------------------------------------------------------------------
// scores via fp16x3 MFMA: C[u][s] = scale * q[top_u] . k[s], out as h/l pairs.
// grid: (32 s-tiles, (U+127)/128 u-tiles, 16 b), block 256
// ---------------------------------------------------------------------------
__global__ __launch_bounds__(256) void scores_mfma(
    const _Float16* __restrict__ qh, const _Float16* __restrict__ ql,
    const _Float16* __restrict__ kh, const _Float16* __restrict__ kl,
    const int* __restrict__ topidx,
    _Float16* __restrict__ sh, _Float16* __restrict__ sl, int U)
{
    const int b = blockIdx.z;
    const int s0 = blockIdx.x * 128;
    const int u0 = blockIdx.y * 128;
    const size_t perB = (size_t)D_DIM * L_DIM;
    const _Float16* qh_b = qh + (size_t)b * perB;
    const _Float16* ql_b = ql + (size_t)b * perB;
    const _Float16* kh_b = kh + (size_t)b * perB;
    const _Float16* kl_b = kl + (size_t)b * perB;
    _Float16* sh_b = sh + (size_t)b * (size_t)U * L_DIM;
    _Float16* sl_b = sl + (size_t)b * (size_t)U * L_DIM;

    __shared__ _Float16 ldsAh[4096], ldsAl[4096];   // gathered q [u][32]
    __shared__ _Float16 ldsBh[4096], ldsBl[4096];   // k [s][32]
    __shared__ int arow[128];

    const int tid = threadIdx.x;
    const int w4 = tid >> 6, lane = tid & 63;
    const int lr = lane & 15, quad = lane >> 4;
    const int wu = w4 >> 1, wn = w4 & 1;

    if (tid < 128) {
        int u = u0 + tid;
        arow[tid] = topidx[b * U + (u < U ? u : U - 1)];
    }
    __syncthreads();

    f32x4 acc[4][4] = {};

    for (int k0 = 0; k0 < 512; k0 += 32) {
        #pragma unroll
        for (int t = 0; t < 2; t++) {
            int c = w4 * 128 + t * 64 + lane;
            int row = c >> 2, part = c & 3;
            size_t go = (size_t)arow[row] * 512 + k0 + part * 8;
            size_t ko = (size_t)(s0 + row) * 512 + k0 + part * 8;
            int base = (w4 * 128 + t * 64) * 8;
            gld16(qh_b + go, ldsAh + base);
            gld16(ql_b + go, ldsAl + base);
            gld16(kh_b + ko, ldsBh + base);
            gld16(kl_b + ko, ldsBl + base);
        }
        __syncthreads();

        half8 fAh[4], fAl[4];
        #pragma unroll
        for (int i = 0; i < 4; i++) {
            int u = wu * 64 + i * 16 + lr;
            fAh[i] = *(const half8*)(ldsAh + u * 32 + quad * 8);
            fAl[i] = *(const half8*)(ldsAl + u * 32 + quad * 8);
        }
        #pragma unroll
        for (int j = 0; j < 4; j++) {
            int s = wn * 64 + j * 16 + lr;
            half8 fBh = *(const half8*)(ldsBh + s * 32 + quad * 8);
            half8 fBl = *(const half8*)(ldsBl + s * 32 + quad * 8);
            #pragma unroll
            for (int i = 0; i < 4; i++) {
                acc[i][j] = __builtin_amdgcn_mfma_f32_16x16x32_f16(fAh[i], fBh, acc[i][j], 0, 0, 0);
                acc[i][j] = __builtin_amdgcn_mfma_f32_16x16x32_f16(fAl[i], fBh, acc[i][j], 0, 0, 0);
                acc[i][j] = __builtin_amdgcn_mfma_f32_16x16x32_f16(fAh[i], fBl, acc[i][j], 0, 0, 0);
            }
        }
        __syncthreads();
    }

    const float scale = 0.044194173824159216f;   // 1/sqrt(512)
    #pragma unroll
    for (int i = 0; i < 4; i++) {
        #pragma unroll
        for (int r = 0; r < 4; r++) {
            int u = u0 + wu * 64 + i * 16 + quad * 4 + r;
            if (u < U) {
                #pragma unroll
                for (int j = 0; j < 4; j++) {
                    int s = s0 + wn * 64 + j * 16 + lr;
                    float val = acc[i][j][r] * scale;
                    _Float16 hi = (_Float16)val;
                    size_t off = (size_t)u * L_DIM + s;
                    sh_b[off] = hi;
                    sl_b[off] = (_Float16)(val - (float)hi);
                }
            }
        }
    }
}

// ---------------------------------------------------------------------------
// Row softmax over 4096, h/l in, h/l out (in place). grid (B*U), block 256
// ---------------------------------------------------------------------------
__global__ __launch_bounds__(256) void softmax_hl(_Float16* __restrict__ sh,
                                                  _Float16* __restrict__ sl)
{
    _Float16* hrow = sh + (size_t)blockIdx.x * L_DIM;
    _Float16* lrow = sl + (size_t)blockIdx.x * L_DIM;
    const int tid = threadIdx.x;
    float x[16];
    #pragma unroll
    for (int t = 0; t < 2; t++) {
        half8 h8 = *(const half8*)(hrow + tid * 8 + t * 2048);
        half8 l8 = *(const half8*)(lrow + tid * 8 + t * 2048);
        #pragma unroll
        for (int i = 0; i < 8; i++) x[t * 8 + i] = (float)h8[i] + (float)l8[i];
    }
    __shared__ float red[256];
    float lm = -__builtin_inff();
    #pragma unroll
    for (int i = 0; i < 16; i++) lm = fmaxf(lm, x[i]);
    red[tid] = lm;
    __syncthreads();
    for (int o = 128; o > 0; o >>= 1) {
        if (tid < o) red[tid] = fmaxf(red[tid], red[tid + o]);
        __syncthreads();
    }
    float m = red[0];
    __syncthreads();
    float ls = 0.f;
    #pragma unroll
    for (int i = 0; i < 16; i++) { x[i] = __expf(x[i] - m); ls += x[i]; }
    red[tid] = ls;
    __syncthreads();
    for (int o = 128; o > 0; o >>= 1) {
        if (tid < o) red[tid] += red[tid + o];
        __syncthreads();
    }
    float inv = 1.f / red[0];
    #pragma unroll
    for (int t = 0; t < 2; t++) {
        half8 h8, l8;
        #pragma unroll
        for (int i = 0; i < 8; i++) {
            float val = x[t * 8 + i] * inv;
            _Float16 hi = (_Float16)val;
            h8[i] = hi;
            l8[i] = (_Float16)(val - (float)hi);
        }
        *(half8*)(hrow + tid * 8 + t * 2048) = h8;
        *(half8*)(lrow + tid * 8 + t * 2048) = l8;
    }
}

// ---------------------------------------------------------------------------
// upd via fp16x3 MFMA: C[u][dd] = sum_s attn[u][s] * v[s][dd]; scatter rows.
// A = attn h/l (k-contig), B = v tiles transposed into LDS with chunk swizzle.
// grid: ((U+127)/128 u-tiles, 4 dd-tiles, 16 b), block 256
// ---------------------------------------------------------------------------
__global__ __launch_bounds__(256) void upd_mfma(
    const _Float16* __restrict__ sh, const _Float16* __restrict__ sl,
    const _Float16* __restrict__ vh, const _Float16* __restrict__ vl,
    const int* __restrict__ topidx, float* __restrict__ out, int U)
{
    const int b = blockIdx.z;
    const int n0 = blockIdx.y * 128;
    const int u0 = blockIdx.x * 128;
    const size_t perB = (size_t)D_DIM * L_DIM;
    const _Float16* ah_b = sh + (size_t)b * (size_t)U * L_DIM;
    const _Float16* al_b = sl + (size_t)b * (size_t)U * L_DIM;
    const _Float16* vh_b = vh + (size_t)b * perB;
    const _Float16* vl_b = vl + (size_t)b * perB;

    __shared__ _Float16 ldsAh[4096], ldsAl[4096];   // attn [u][32]
    __shared__ _Float16 ldsBh[4096], ldsBl[4096];   // vT   [dd][32] (chunk-swizzled)

    const int tid = threadIdx.x;
    const int w4 = tid >> 6, lane = tid & 63;
    const int lr = lane & 15, quad = lane >> 4;
    const int wu = w4 >> 1, wd = w4 & 1;

    // B-staging assignment: part = tid&15 (dd chunk), spair = tid>>4 (s pair)
    const int part = tid & 15, spair = tid >> 4;
    const int s_b = spair * 2;
    const int colw = ((spair >> 2) + part) & 3;
    const int so2 = (s_b & 7);

    f32x4 acc[4][4] = {};

    for (int k0 = 0; k0 < L_DIM; k0 += 32) {
        // A: attn rows via global_load_lds
        #pragma unroll
        for (int t = 0; t < 2; t++) {
            int c = w4 * 128 + t * 64 + lane;
            int u = c >> 2, pt = c & 3;
            int urow = u0 + u; if (urow >= U) urow = U - 1;
            size_t ao = (size_t)urow * L_DIM + k0 + pt * 8;
            int base = (w4 * 128 + t * 64) * 8;
            gld16(ah_b + ao, ldsAh + base);
            gld16(al_b + ao, ldsAl + base);
        }
        // B: v rows -> transposed LDS via packed b32 writes
        {
            const _Float16* s0p = vh_b + (size_t)(k0 + s_b) * 512 + n0 + part * 8;
            const _Float16* s1p = s0p + 512;
            ushort8 a0 = *(const ushort8*)s0p;
            ushort8 a1 = *(const ushort8*)s1p;
            const _Float16* t0p = vl_b + (size_t)(k0 + s_b) * 512 + n0 + part * 8;
            const _Float16* t1p = t0p + 512;
            ushort8 c0 = *(const ushort8*)t0p;
            ushort8 c1 = *(const ushort8*)t1p;
            #pragma unroll
            for (int t = 0; t < 8; t++) {
                int dd = part * 8 + t;
                unsigned int ph = (unsigned int)a0[t] | ((unsigned int)a1[t] << 16);
                unsigned int pl = (unsigned int)c0[t] | ((unsigned int)c1[t] << 16);
                *(unsigned int*)(ldsBh + dd * 32 + colw * 8 + so2) = ph;
                *(unsigned int*)(ldsBl + dd * 32 + colw * 8 + so2) = pl;
            }
        }
        __syncthreads();

        half8 fAh[4], fAl[4];
        #pragma unroll
        for (int i = 0; i < 4; i++) {
            int u = wu * 64 + i * 16 + lr;
            fAh[i] = *(const half8*)(ldsAh + u * 32 + quad * 8);
            fAl[i] = *(const half8*)(ldsAl + u * 32 + quad * 8);
        }
        #pragma unroll
        for (int j = 0; j < 4; j++) {
            int dd = wd * 64 + j * 16 + lr;
            int col = (quad + (dd >> 3)) & 3;
            half8 fBh = *(const half8*)(ldsBh + dd * 32 + col * 8);
            half8 fBl = *(const half8*)(ldsBl + dd * 32 + col * 8);
            #pragma unroll
            for (int i = 0; i < 4; i++) {
                acc[i][j] = __builtin_amdgcn_mfma_f32_16x16x32_f16(fAh[i], fBh, acc[i][j], 0, 0, 0);
                acc[i][j] = __builtin_amdgcn_mfma_f32_16x16x32_f16(fAl[i], fBh, acc[i][j], 0, 0, 0);
                acc[i][j] = __builtin_amdgcn_mfma_f32_16x16x32_f16(fAh[i], fBl, acc[i][j], 0, 0, 0);
            }
        }
        __syncthreads();
    }

    #pragma unroll
    for (int i = 0; i < 4; i++) {
        #pragma unroll
        for (int r = 0; r < 4; r++) {
            int u = u0 + wu * 64 + i * 16 + quad * 4 + r;
            if (u < U) {
                int lrow = topidx[b * U + u];
                #pragma unroll
                for (int j = 0; j < 4; j++) {
                    int dd = n0 + wd * 64 + j * 16 + lr;
                    out[(size_t)b * perB + (size_t)lrow * 512 + dd] = acc[i][j][r];
                }
            }
        }
    }
}

// ---------------------------------------------------------------------------
extern "C" void kernel_launch(void* const* d_in, const int* in_sizes, int n_in,
                              void* d_out, int out_size, void* d_ws, size_t ws_size,
                              hipStream_t stream)
{
    const float* x1 = (const float*)d_in[0];
    const float* x2 = (const float*)d_in[1];
    const float* Wq = (const float*)d_in[2];
    const float* bq = (const float*)d_in[3];
    const float* Wk = (const float*)d_in[4];
    const float* bk = (const float*)d_in[5];
    const float* Wv = (const float*)d_in[6];
    const float* bv = (const float*)d_in[7];
    const int*  idx = (const int*)d_in[8];
    const int U = in_sizes[8];            // 450

    float* out = (float*)d_out;

    const size_t perB = (size_t)D_DIM * L_DIM;          // 2,097,152
    const size_t tenH = (size_t)BATCH * perB;           // 33,554,432 halves
    _Float16* qh = (_Float16*)d_ws;
    _Float16* ql = qh + tenH;
    _Float16* kh = ql + tenH;
    _Float16* kl = kh + tenH;
    _Float16* vh = kl + tenH;
    _Float16* vl = vh + tenH;
    float* S = (float*)(vl + tenH);                     // 118 MB union region

    // proj-phase aliases inside S:
    _Float16* XTh = (_Float16*)S;
    _Float16* XTl = XTh + (size_t)8 * L_DIM * 512;
    _Float16* Wh  = XTl + (size_t)8 * L_DIM * 512;
    _Float16* Wl  = Wh + (size_t)3 * 512 * 512;

    // post-proj aliases inside S:
    _Float16* sh = (_Float16*)S;
    _Float16* sl = sh + (size_t)BATCH * (size_t)U * L_DIM;
    float* Mbuf  = (float*)(sl + (size_t)BATCH * (size_t)U * L_DIM);
    float* vmean = Mbuf + (size_t)BATCH * L_DIM;
    float* part  = vmean + (size_t)BATCH * D_DIM;
    int* topidx  = (int*)(part + (size_t)BATCH * 32 * D_DIM);

    // 1. split W
    convert_w<<<dim3(1024, 3), 256, 0, stream>>>(Wq, Wk, Wv, Wh, Wl);

    // 2. projections (two 8-batch phases), outputs q/k/v as hi/lo fp16
    for (int phase = 0; phase < 2; phase++) {
        convert_x<<<dim3(64, 8, 8), 256, 0, stream>>>(x1, x2, XTh, XTl, phase);
        proj_mfma<<<dim3(L_DIM / 128, D_DIM / 128, 8 * 3), 256, 0, stream>>>(
            Wh, Wl, XTh, XTl, bq, bk, bv, qh, ql, kh, kl, vh, vl, phase);
    }

    // 3. v mean + output fill
    vmean_partial<<<dim3(32, BATCH), 512, 0, stream>>>(vh, vl, part);
    vmean_reduce<<<BATCH, 512, 0, stream>>>(part, vmean);
    fill_out<<<BATCH * 64, 256, 0, stream>>>(vmean, out);

    // 4. sampled QK^T -> M (fused reduction, no materialization)
    qks_mfma<<<dim3(L_DIM / 128, BATCH), 256, 0, stream>>>(
        qh, ql, kh, kl, idx, Mbuf, U);

    // 5. top-U per batch
    topk_sort<<<BATCH, 512, 0, stream>>>(Mbuf, topidx, U);

    // 6. scores (h/l out), softmax (h/l in place), attn @ V scatter
    const int utiles = (U + 127) / 128;
    scores_mfma<<<dim3(L_DIM / 128, utiles, BATCH), 256, 0, stream>>>(
        qh, ql, kh, kl, topidx, sh, sl, U);
    softmax_hl<<<BATCH * U, 256, 0, stream>>>(sh, sl);
    upd_mfma<<<dim3(utiles, D_DIM / 128, BATCH), 256, 0, stream>>>(
        sh, sl, vh, vl, topidx, out, U);
}

// Round 4
// 1100.424 us; speedup vs baseline: 2.7355x; 1.1189x over previous
//
#include <hip/hip_runtime.h>
#include <cstdint>
#include <cstddef>

#define L_DIM 4096
#define D_DIM 512
#define CIN   256
#define BATCH 16
#define KSPLIT 4

typedef _Float16 half8 __attribute__((ext_vector_type(8)));
typedef unsigned short ushort8 __attribute__((ext_vector_type(8)));
typedef float f32x4 __attribute__((ext_vector_type(4)));

__device__ __forceinline__ void gld16(const _Float16* g, _Float16* l) {
    __builtin_amdgcn_global_load_lds(
        (const __attribute__((address_space(1))) unsigned int*)g,
        (__attribute__((address_space(3))) unsigned int*)l,
        16, 0, 0);
}

// ---------------------------------------------------------------------------
// Split W (3 x 512x512 fp32) into fp16 hi/lo. grid (1024,3), block 256
// ---------------------------------------------------------------------------
__global__ __launch_bounds__(256) void convert_w(
    const float* __restrict__ Wq, const float* __restrict__ Wk,
    const float* __restrict__ Wv,
    _Float16* __restrict__ Wh, _Float16* __restrict__ Wl)
{
    const int w = blockIdx.y;
    const float* src = (w == 0) ? Wq : (w == 1) ? Wk : Wv;
    int i = blockIdx.x * 256 + threadIdx.x;
    float xv = src[i];
    _Float16 hi = (_Float16)xv;
    Wh[(size_t)w * 262144 + i] = hi;
    Wl[(size_t)w * 262144 + i] = (_Float16)(xv - (float)hi);
}

// ---------------------------------------------------------------------------
// Transpose + split X. Per phase 8 batches. grid (64, 8, 8), block 256.
// ---------------------------------------------------------------------------
__global__ __launch_bounds__(256) void convert_x(
    const float* __restrict__ x1, const float* __restrict__ x2,
    _Float16* __restrict__ XTh, _Float16* __restrict__ XTl, int phase)
{
    const int bb = blockIdx.z;
    const int b = phase * 8 + bb;
    const int s0 = blockIdx.x * 64;
    const int c0 = blockIdx.y * 64;
    __shared__ float t[64][65];
    const int tid = threadIdx.x;
    const int g = tid >> 6, sy = tid & 63;
    const float* src = (c0 < CIN)
        ? (x1 + (size_t)b * CIN * L_DIM + (size_t)c0 * L_DIM)
        : (x2 + (size_t)b * CIN * L_DIM + (size_t)(c0 - CIN) * L_DIM);
    #pragma unroll
    for (int r = 0; r < 16; r++) {
        int cl = g * 16 + r;
        t[cl][sy] = src[(size_t)cl * L_DIM + s0 + sy];
    }
    __syncthreads();
    _Float16* outh = XTh + (size_t)bb * L_DIM * 512 + (size_t)s0 * 512 + c0;
    _Float16* outl = XTl + (size_t)bb * L_DIM * 512 + (size_t)s0 * 512 + c0;
    #pragma unroll
    for (int r = 0; r < 16; r++) {
        int sl = g * 16 + r;
        float xv = t[sy][sl];
        _Float16 hi = (_Float16)xv;
        float lo = xv - (float)hi;
        outh[(size_t)sl * 512 + sy] = hi;
        outl[(size_t)sl * 512 + sy] = (_Float16)lo;
    }
}

// ---------------------------------------------------------------------------
// Projection via fp16x3 MFMA, epilogue writes hi/lo fp16 pairs.
// grid: (32, 4, 24), block 256
// ---------------------------------------------------------------------------
__global__ __launch_bounds__(256) void proj_mfma(
    const _Float16* __restrict__ Wh, const _Float16* __restrict__ Wl,
    const _Float16* __restrict__ XTh, const _Float16* __restrict__ XTl,
    const float* __restrict__ bq, const float* __restrict__ bk,
    const float* __restrict__ bv,
    _Float16* __restrict__ qh, _Float16* __restrict__ ql,
    _Float16* __restrict__ kh, _Float16* __restrict__ kl,
    _Float16* __restrict__ vh, _Float16* __restrict__ vl,
    int phase)
{
    const int z = blockIdx.z;
    const int bb = z / 3, w = z % 3;
    const int b = phase * 8 + bb;
    const _Float16* Ah_g = Wh + (size_t)w * 262144;
    const _Float16* Al_g = Wl + (size_t)w * 262144;
    const _Float16* Bh_g = XTh + (size_t)bb * ((size_t)L_DIM * 512);
    const _Float16* Bl_g = XTl + (size_t)bb * ((size_t)L_DIM * 512);
    const float* bias = (w == 0) ? bq : (w == 1) ? bk : bv;
    _Float16* outh = ((w == 0) ? qh : (w == 1) ? kh : vh) + (size_t)b * ((size_t)D_DIM * L_DIM);
    _Float16* outl = ((w == 0) ? ql : (w == 1) ? kl : vl) + (size_t)b * ((size_t)D_DIM * L_DIM);

    const int m0 = blockIdx.y * 128;
    const int n0 = blockIdx.x * 128;

    __shared__ _Float16 lds[4 * 128 * 32];
    _Float16* ldsA_h = lds;
    _Float16* ldsA_l = lds + 4096;
    _Float16* ldsB_h = lds + 8192;
    _Float16* ldsB_l = lds + 12288;

    const int tid = threadIdx.x;
    const int w4 = tid >> 6, lane = tid & 63;
    const int lr = lane & 15, quad = lane >> 4;
    const int wr = w4 >> 1, wc = w4 & 1;

    f32x4 acc[4][4] = {};

    const int q1 = w4 * 128 + lane, q2 = q1 + 64;
    const int r1 = q1 >> 2, c41 = q1 & 3;
    const int r2 = q2 >> 2, c42 = q2 & 3;

    const _Float16* pAh1 = Ah_g + (size_t)(m0 + r1) * 512 + c41 * 8;
    const _Float16* pAh2 = Ah_g + (size_t)(m0 + r2) * 512 + c42 * 8;
    const _Float16* pAl1 = Al_g + (size_t)(m0 + r1) * 512 + c41 * 8;
    const _Float16* pAl2 = Al_g + (size_t)(m0 + r2) * 512 + c42 * 8;
    const _Float16* pBh1 = Bh_g + (size_t)(n0 + r1) * 512 + c41 * 8;
    const _Float16* pBh2 = Bh_g + (size_t)(n0 + r2) * 512 + c42 * 8;
    const _Float16* pBl1 = Bl_g + (size_t)(n0 + r1) * 512 + c41 * 8;
    const _Float16* pBl2 = Bl_g + (size_t)(n0 + r2) * 512 + c42 * 8;

    _Float16* d1 = (_Float16*)(lds) + (size_t)(w4 * 128) * 8;
    _Float16* d2 = (_Float16*)(lds) + (size_t)(w4 * 128 + 64) * 8;

    for (int k0 = 0; k0 < 512; k0 += 32) {
        if (k0) __syncthreads();
        gld16(pAh1 + k0, d1);
        gld16(pAh2 + k0, d2);
        gld16(pAl1 + k0, d1 + 4096);
        gld16(pAl2 + k0, d2 + 4096);
        gld16(pBh1 + k0, d1 + 8192);
        gld16(pBh2 + k0, d2 + 8192);
        gld16(pBl1 + k0, d1 + 12288);
        gld16(pBl2 + k0, d2 + 12288);
        __syncthreads();

        half8 fAh[4], fAl[4];
        #pragma unroll
        for (int i = 0; i < 4; i++) {
            int m = wr * 64 + i * 16 + lr;
            fAh[i] = *(const half8*)(ldsA_h + m * 32 + quad * 8);
            fAl[i] = *(const half8*)(ldsA_l + m * 32 + quad * 8);
        }
        #pragma unroll
        for (int j = 0; j < 4; j++) {
            int n = wc * 64 + j * 16 + lr;
            half8 fBh = *(const half8*)(ldsB_h + n * 32 + quad * 8);
            half8 fBl = *(const half8*)(ldsB_l + n * 32 + quad * 8);
            #pragma unroll
            for (int i = 0; i < 4; i++) {
                acc[i][j] = __builtin_amdgcn_mfma_f32_16x16x32_f16(fAh[i], fBh, acc[i][j], 0, 0, 0);
                acc[i][j] = __builtin_amdgcn_mfma_f32_16x16x32_f16(fAl[i], fBh, acc[i][j], 0, 0, 0);
                acc[i][j] = __builtin_amdgcn_mfma_f32_16x16x32_f16(fAh[i], fBl, acc[i][j], 0, 0, 0);
            }
        }
    }

    #pragma unroll
    for (int i = 0; i < 4; i++) {
        int mg = m0 + wr * 64 + i * 16 + quad * 4;
        #pragma unroll
        for (int r = 0; r < 4; r++) {
            float bvv = bias[mg + r];
            #pragma unroll
            for (int j = 0; j < 4; j++) {
                int ng = n0 + wc * 64 + j * 16 + lr;
                float val = acc[i][j][r] + bvv;
                _Float16 hi = (_Float16)val;
                size_t off = (size_t)(mg + r) * L_DIM + ng;
                outh[off] = hi;
                outl[off] = (_Float16)(val - (float)hi);
            }
        }
    }
}

// ---------------------------------------------------------------------------
// qks via fp16x3 MFMA, one s-tile per block, partial max/sum out.
// grid: (32 l-tiles, nst s-tiles, 16 b), block 256
// ---------------------------------------------------------------------------
__global__ __launch_bounds__(256) void qks_mfma(
    const _Float16* __restrict__ qh, const _Float16* __restrict__ ql,
    const _Float16* __restrict__ kh, const _Float16* __restrict__ kl,
    const int* __restrict__ idx_sample,
    float* __restrict__ Mmax, float* __restrict__ Msum, int U, int nst)
{
    const int b = blockIdx.z;
    const int stile = blockIdx.y;
    const int l0 = blockIdx.x * 128;
    const int s0 = stile * 128;
    const size_t perB = (size_t)D_DIM * L_DIM;
    const _Float16* qh_b = qh + (size_t)b * perB;
    const _Float16* ql_b = ql + (size_t)b * perB;
    const _Float16* kh_b = kh + (size_t)b * perB;
    const _Float16* kl_b = kl + (size_t)b * perB;

    __shared__ _Float16 ldsAh[4096], ldsAl[4096];   // gathered k [s][32]
    __shared__ _Float16 ldsBh[4096], ldsBl[4096];   // q [l][32]
    __shared__ int sidx[128];
    __shared__ float redm[8][128];
    __shared__ float reds[8][128];

    const int tid = threadIdx.x;
    const int w4 = tid >> 6, lane = tid & 63;
    const int lr = lane & 15, quad = lane >> 4;
    const int ws = w4 >> 1, wl = w4 & 1;

    if (tid < 128) {
        int s = s0 + tid;
        sidx[tid] = (s < U) ? idx_sample[s] : idx_sample[0];
    }
    __syncthreads();

    f32x4 acc[4][4] = {};

    for (int k0 = 0; k0 < 512; k0 += 32) {
        #pragma unroll
        for (int t = 0; t < 2; t++) {
            int c = w4 * 128 + t * 64 + lane;
            int row = c >> 2, part = c & 3;
            int krow = sidx[row];
            size_t go = (size_t)krow * 512 + k0 + part * 8;
            size_t qo = (size_t)(l0 + row) * 512 + k0 + part * 8;
            int base = (w4 * 128 + t * 64) * 8;
            gld16(kh_b + go, ldsAh + base);
            gld16(kl_b + go, ldsAl + base);
            gld16(qh_b + qo, ldsBh + base);
            gld16(ql_b + qo, ldsBl + base);
        }
        __syncthreads();

        half8 fAh[4], fAl[4];
        #pragma unroll
        for (int i = 0; i < 4; i++) {
            int s = ws * 64 + i * 16 + lr;
            fAh[i] = *(const half8*)(ldsAh + s * 32 + quad * 8);
            fAl[i] = *(const half8*)(ldsAl + s * 32 + quad * 8);
        }
        #pragma unroll
        for (int j = 0; j < 4; j++) {
            int l = wl * 64 + j * 16 + lr;
            half8 fBh = *(const half8*)(ldsBh + l * 32 + quad * 8);
            half8 fBl = *(const half8*)(ldsBl + l * 32 + quad * 8);
            #pragma unroll
            for (int i = 0; i < 4; i++) {
                acc[i][j] = __builtin_amdgcn_mfma_f32_16x16x32_f16(fAh[i], fBh, acc[i][j], 0, 0, 0);
                acc[i][j] = __builtin_amdgcn_mfma_f32_16x16x32_f16(fAl[i], fBh, acc[i][j], 0, 0, 0);
                acc[i][j] = __builtin_amdgcn_mfma_f32_16x16x32_f16(fAh[i], fBl, acc[i][j], 0, 0, 0);
            }
        }
        __syncthreads();
    }

    float runmax[4], runsum[4];
    #pragma unroll
    for (int j = 0; j < 4; j++) { runmax[j] = -__builtin_inff(); runsum[j] = 0.f; }
    #pragma unroll
    for (int i = 0; i < 4; i++) {
        #pragma unroll
        for (int r = 0; r < 4; r++) {
            int sg = s0 + ws * 64 + i * 16 + quad * 4 + r;
            if (sg < U) {
                #pragma unroll
                for (int j = 0; j < 4; j++) {
                    runmax[j] = fmaxf(runmax[j], acc[i][j][r]);
                    runsum[j] += acc[i][j][r];
                }
            }
        }
    }
    #pragma unroll
    for (int j = 0; j < 4; j++) {
        int l = wl * 64 + j * 16 + lr;
        redm[ws * 4 + quad][l] = runmax[j];
        reds[ws * 4 + quad][l] = runsum[j];
    }
    __syncthreads();
    if (tid < 128) {
        float gm = -__builtin_inff(), gs = 0.f;
        #pragma unroll
        for (int t = 0; t < 8; t++) { gm = fmaxf(gm, redm[t][tid]); gs += reds[t][tid]; }
        size_t o = ((size_t)b * nst + stile) * L_DIM + l0 + tid;
        Mmax[o] = gm;
        Msum[o] = gs;
    }
}

// ---------------------------------------------------------------------------
// Per-batch top-U: reduce partials -> M, binary-search threshold on key bits,
// compact indices (set semantics). grid (B), block 512.
// ---------------------------------------------------------------------------
__global__ __launch_bounds__(512) void topk_select(
    const float* __restrict__ Mmax, const float* __restrict__ Msum,
    int* __restrict__ topidx, int U, int nst)
{
    const int b = blockIdx.x;
    const int tid = threadIdx.x;
    __shared__ int wcnt[8];
    __shared__ int basec;

    unsigned mykey[8];
    #pragma unroll
    for (int t = 0; t < 8; t++) {
        int l = t * 512 + tid;
        float gm = -__builtin_inff(), gs = 0.f;
        for (int st = 0; st < nst; st++) {
            size_t o = ((size_t)b * nst + st) * L_DIM + l;
            gm = fmaxf(gm, Mmax[o]);
            gs += Msum[o];
        }
        float M = gm - gs * (1.f / (float)L_DIM);
        unsigned bits = __float_as_uint(M);
        mykey[t] = (bits & 0x80000000u) ? ~bits : (bits | 0x80000000u);
    }
    if (tid == 0) basec = 0;

    const int wv = tid >> 6, lane = tid & 63;
    unsigned lo = 0u, hi = 0xFFFFFFFFu;
    while (lo < hi) {
        unsigned hl = hi - lo;
        unsigned mid = lo + (hl >> 1) + (hl & 1u);   // ceil midpoint, overflow-safe
        int c = 0;
        #pragma unroll
        for (int t = 0; t < 8; t++) c += (mykey[t] >= mid) ? 1 : 0;
        #pragma unroll
        for (int o = 32; o > 0; o >>= 1) c += __shfl_down(c, o, 64);
        if (lane == 0) wcnt[wv] = c;
        __syncthreads();
        int total = 0;
        #pragma unroll
        for (int i = 0; i < 8; i++) total += wcnt[i];
        if (total >= U) lo = mid; else hi = mid - 1;
        __syncthreads();
    }
    #pragma unroll
    for (int t = 0; t < 8; t++) {
        if (mykey[t] >= lo) {
            int pos = atomicAdd(&basec, 1);
            if (pos < U) topidx[b * U + pos] = t * 512 + tid;
        }
    }
}

// ---------------------------------------------------------------------------
// v mean from hi/lo halves
// ---------------------------------------------------------------------------
__global__ __launch_bounds__(512) void vmean_partial(
    const _Float16* __restrict__ vh, const _Float16* __restrict__ vl,
    float* __restrict__ partial)
{
    const int ch = blockIdx.x, b = blockIdx.y;
    const int d = threadIdx.x;
    const _Float16* vhb = vh + (size_t)b * ((size_t)D_DIM * L_DIM);
    const _Float16* vlb = vl + (size_t)b * ((size_t)D_DIM * L_DIM);
    float acc = 0.f;
    const int lbeg = ch * 128;
    for (int l = lbeg; l < lbeg + 128; l++)
        acc += (float)vhb[(size_t)l * D_DIM + d] + (float)vlb[(size_t)l * D_DIM + d];
    partial[((size_t)b * 32 + ch) * D_DIM + d] = acc;
}

__global__ __launch_bounds__(512) void vmean_reduce(const float* __restrict__ partial,
                                                    float* __restrict__ vmean)
{
    const int b = blockIdx.x;
    const int d = threadIdx.x;
    float acc = 0.f;
    for (int ch = 0; ch < 32; ch++) acc += partial[((size_t)b * 32 + ch) * D_DIM + d];
    vmean[b * D_DIM + d] = acc * (1.f / (float)L_DIM);
}

__global__ __launch_bounds__(256) void fill_out(const float* __restrict__ vmean,
                                                float* __restrict__ out)
{
    const int z = blockIdx.x;
    const int b = z >> 6, lch = z & 63;
    __shared__ float vm[512];
    vm[threadIdx.x] = vmean[b * 512 + threadIdx.x];
    vm[threadIdx.x + 256] = vmean[b * 512 + threadIdx.x + 256];
    __syncthreads();
    float* op = out + (size_t)b * ((size_t)D_DIM * L_DIM) + (size_t)lch * 64 * 512;
    #pragma unroll
    for (int it = 0; it < 32; it++) {
        int flat = (threadIdx.x + it * 256) * 4;
        int d = flat & 511;
        float4 r = { vm[d], vm[d + 1], vm[d + 2], vm[d + 3] };
        *(float4*)&op[flat] = r;
    }
}

// Zero selected output rows ahead of atomic accumulation. grid (U, B), block 256
__global__ __launch_bounds__(256) void zero_sel(const int* __restrict__ topidx,
                                                float* __restrict__ out, int U)
{
    const int u = blockIdx.x, b = blockIdx.y;
    int row = topidx[b * U + u];
    float2 z = { 0.f, 0.f };
    *(float2*)&out[(size_t)b * ((size_t)D_DIM * L_DIM) + (size_t)row * 512
                   + threadIdx.x * 2] = z;
}

// ---------------------------------------------------------------------------
// scores via fp16x3 MFMA: C[u][s] = scale * q[top_u] . k[s], out as h/l pairs.
// grid: (32 s-tiles, (U+127)/128 u-tiles, 16 b), block 256
// ---------------------------------------------------------------------------
__global__ __launch_bounds__(256) void scores_mfma(
    const _Float16* __restrict__ qh, const _Float16* __restrict__ ql,
    const _Float16* __restrict__ kh, const _Float16* __restrict__ kl,
    const int* __restrict__ topidx,
    _Float16* __restrict__ sh, _Float16* __restrict__ sl, int U)
{
    const int b = blockIdx.z;
    const int s0 = blockIdx.x * 128;
    const int u0 = blockIdx.y * 128;
    const size_t perB = (size_t)D_DIM * L_DIM;
    const _Float16* qh_b = qh + (size_t)b * perB;
    const _Float16* ql_b = ql + (size_t)b * perB;
    const _Float16* kh_b = kh + (size_t)b * perB;
    const _Float16* kl_b = kl + (size_t)b * perB;
    _Float16* sh_b = sh + (size_t)b * (size_t)U * L_DIM;
    _Float16* sl_b = sl + (size_t)b * (size_t)U * L_DIM;

    __shared__ _Float16 ldsAh[4096], ldsAl[4096];   // gathered q [u][32]
    __shared__ _Float16 ldsBh[4096], ldsBl[4096];   // k [s][32]
    __shared__ int arow[128];

    const int tid = threadIdx.x;
    const int w4 = tid >> 6, lane = tid & 63;
    const int lr = lane & 15, quad = lane >> 4;
    const int wu = w4 >> 1, wn = w4 & 1;

    if (tid < 128) {
        int u = u0 + tid;
        arow[tid] = topidx[b * U + (u < U ? u : U - 1)];
    }
    __syncthreads();

    f32x4 acc[4][4] = {};

    for (int k0 = 0; k0 < 512; k0 += 32) {
        #pragma unroll
        for (int t = 0; t < 2; t++) {
            int c = w4 * 128 + t * 64 + lane;
            int row = c >> 2, part = c & 3;
            size_t go = (size_t)arow[row] * 512 + k0 + part * 8;
            size_t ko = (size_t)(s0 + row) * 512 + k0 + part * 8;
            int base = (w4 * 128 + t * 64) * 8;
            gld16(qh_b + go, ldsAh + base);
            gld16(ql_b + go, ldsAl + base);
            gld16(kh_b + ko, ldsBh + base);
            gld16(kl_b + ko, ldsBl + base);
        }
        __syncthreads();

        half8 fAh[4], fAl[4];
        #pragma unroll
        for (int i = 0; i < 4; i++) {
            int u = wu * 64 + i * 16 + lr;
            fAh[i] = *(const half8*)(ldsAh + u * 32 + quad * 8);
            fAl[i] = *(const half8*)(ldsAl + u * 32 + quad * 8);
        }
        #pragma unroll
        for (int j = 0; j < 4; j++) {
            int s = wn * 64 + j * 16 + lr;
            half8 fBh = *(const half8*)(ldsBh + s * 32 + quad * 8);
            half8 fBl = *(const half8*)(ldsBl + s * 32 + quad * 8);
            #pragma unroll
            for (int i = 0; i < 4; i++) {
                acc[i][j] = __builtin_amdgcn_mfma_f32_16x16x32_f16(fAh[i], fBh, acc[i][j], 0, 0, 0);
                acc[i][j] = __builtin_amdgcn_mfma_f32_16x16x32_f16(fAl[i], fBh, acc[i][j], 0, 0, 0);
                acc[i][j] = __builtin_amdgcn_mfma_f32_16x16x32_f16(fAh[i], fBl, acc[i][j], 0, 0, 0);
            }
        }
        __syncthreads();
    }

    const float scale = 0.044194173824159216f;   // 1/sqrt(512)
    #pragma unroll
    for (int i = 0; i < 4; i++) {
        #pragma unroll
        for (int r = 0; r < 4; r++) {
            int u = u0 + wu * 64 + i * 16 + quad * 4 + r;
            if (u < U) {
                #pragma unroll
                for (int j = 0; j < 4; j++) {
                    int s = s0 + wn * 64 + j * 16 + lr;
                    float val = acc[i][j][r] * scale;
                    _Float16 hi = (_Float16)val;
                    size_t off = (size_t)u * L_DIM + s;
                    sh_b[off] = hi;
                    sl_b[off] = (_Float16)(val - (float)hi);
                }
            }
        }
    }
}

// ---------------------------------------------------------------------------
// Row softmax over 4096, h/l in, h/l out (in place). grid (B*U), block 256
// ---------------------------------------------------------------------------
__global__ __launch_bounds__(256) void softmax_hl(_Float16* __restrict__ sh,
                                                  _Float16* __restrict__ sl)
{
    _Float16* hrow = sh + (size_t)blockIdx.x * L_DIM;
    _Float16* lrow = sl + (size_t)blockIdx.x * L_DIM;
    const int tid = threadIdx.x;
    float x[16];
    #pragma unroll
    for (int t = 0; t < 2; t++) {
        half8 h8 = *(const half8*)(hrow + tid * 8 + t * 2048);
        half8 l8 = *(const half8*)(lrow + tid * 8 + t * 2048);
        #pragma unroll
        for (int i = 0; i < 8; i++) x[t * 8 + i] = (float)h8[i] + (float)l8[i];
    }
    __shared__ float red[256];
    float lm = -__builtin_inff();
    #pragma unroll
    for (int i = 0; i < 16; i++) lm = fmaxf(lm, x[i]);
    red[tid] = lm;
    __syncthreads();
    for (int o = 128; o > 0; o >>= 1) {
        if (tid < o) red[tid] = fmaxf(red[tid], red[tid + o]);
        __syncthreads();
    }
    float m = red[0];
    __syncthreads();
    float ls = 0.f;
    #pragma unroll
    for (int i = 0; i < 16; i++) { x[i] = __expf(x[i] - m); ls += x[i]; }
    red[tid] = ls;
    __syncthreads();
    for (int o = 128; o > 0; o >>= 1) {
        if (tid < o) red[tid] += red[tid + o];
        __syncthreads();
    }
    float inv = 1.f / red[0];
    #pragma unroll
    for (int t = 0; t < 2; t++) {
        half8 h8, l8;
        #pragma unroll
        for (int i = 0; i < 8; i++) {
            float val = x[t * 8 + i] * inv;
            _Float16 hi = (_Float16)val;
            h8[i] = hi;
            l8[i] = (_Float16)(val - (float)hi);
        }
        *(half8*)(hrow + tid * 8 + t * 2048) = h8;
        *(half8*)(lrow + tid * 8 + t * 2048) = l8;
    }
}

// ---------------------------------------------------------------------------
// upd via fp16x3 MFMA, K-split x4, atomic accumulate into zeroed rows.
// grid: ((U+127)/128 u-tiles, 4 dd-tiles, 16*KSPLIT), block 256
// ---------------------------------------------------------------------------
__global__ __launch_bounds__(256) void upd_mfma(
    const _Float16* __restrict__ sh, const _Float16* __restrict__ sl,
    const _Float16* __restrict__ vh, const _Float16* __restrict__ vl,
    const int* __restrict__ topidx, float* __restrict__ out, int U)
{
    const int zz = blockIdx.z;
    const int b = zz >> 2, ks = zz & 3;
    const int n0 = blockIdx.y * 128;
    const int u0 = blockIdx.x * 128;
    const size_t perB = (size_t)D_DIM * L_DIM;
    const _Float16* ah_b = sh + (size_t)b * (size_t)U * L_DIM;
    const _Float16* al_b = sl + (size_t)b * (size_t)U * L_DIM;
    const _Float16* vh_b = vh + (size_t)b * perB;
    const _Float16* vl_b = vl + (size_t)b * perB;

    __shared__ _Float16 ldsAh[4096], ldsAl[4096];   // attn [u][32]
    __shared__ _Float16 ldsBh[4096], ldsBl[4096];   // vT   [dd][32] (chunk-swizzled)

    const int tid = threadIdx.x;
    const int w4 = tid >> 6, lane = tid & 63;
    const int lr = lane & 15, quad = lane >> 4;
    const int wu = w4 >> 1, wd = w4 & 1;

    const int part = tid & 15, spair = tid >> 4;
    const int s_b = spair * 2;
    const int colw = ((spair >> 2) + part) & 3;
    const int so2 = (s_b & 7);

    f32x4 acc[4][4] = {};

    const int kbeg = ks * (L_DIM / KSPLIT);
    const int kend = kbeg + (L_DIM / KSPLIT);
    for (int k0 = kbeg; k0 < kend; k0 += 32) {
        #pragma unroll
        for (int t = 0; t < 2; t++) {
            int c = w4 * 128 + t * 64 + lane;
            int u = c >> 2, pt = c & 3;
            int urow = u0 + u; if (urow >= U) urow = U - 1;
            size_t ao = (size_t)urow * L_DIM + k0 + pt * 8;
            int base = (w4 * 128 + t * 64) * 8;
            gld16(ah_b + ao, ldsAh + base);
            gld16(al_b + ao, ldsAl + base);
        }
        {
            const _Float16* s0p = vh_b + (size_t)(k0 + s_b) * 512 + n0 + part * 8;
            const _Float16* s1p = s0p + 512;
            ushort8 a0 = *(const ushort8*)s0p;
            ushort8 a1 = *(const ushort8*)s1p;
            const _Float16* t0p = vl_b + (size_t)(k0 + s_b) * 512 + n0 + part * 8;
            const _Float16* t1p = t0p + 512;
            ushort8 c0 = *(const ushort8*)t0p;
            ushort8 c1 = *(const ushort8*)t1p;
            #pragma unroll
            for (int t = 0; t < 8; t++) {
                int dd = part * 8 + t;
                unsigned int ph = (unsigned int)a0[t] | ((unsigned int)a1[t] << 16);
                unsigned int pl = (unsigned int)c0[t] | ((unsigned int)c1[t] << 16);
                *(unsigned int*)(ldsBh + dd * 32 + colw * 8 + so2) = ph;
                *(unsigned int*)(ldsBl + dd * 32 + colw * 8 + so2) = pl;
            }
        }
        __syncthreads();

        half8 fAh[4], fAl[4];
        #pragma unroll
        for (int i = 0; i < 4; i++) {
            int u = wu * 64 + i * 16 + lr;
            fAh[i] = *(const half8*)(ldsAh + u * 32 + quad * 8);
            fAl[i] = *(const half8*)(ldsAl + u * 32 + quad * 8);
        }
        #pragma unroll
        for (int j = 0; j < 4; j++) {
            int dd = wd * 64 + j * 16 + lr;
            int col = (quad + (dd >> 3)) & 3;
            half8 fBh = *(const half8*)(ldsBh + dd * 32 + col * 8);
            half8 fBl = *(const half8*)(ldsBl + dd * 32 + col * 8);
            #pragma unroll
            for (int i = 0; i < 4; i++) {
                acc[i][j] = __builtin_amdgcn_mfma_f32_16x16x32_f16(fAh[i], fBh, acc[i][j], 0, 0, 0);
                acc[i][j] = __builtin_amdgcn_mfma_f32_16x16x32_f16(fAl[i], fBh, acc[i][j], 0, 0, 0);
                acc[i][j] = __builtin_amdgcn_mfma_f32_16x16x32_f16(fAh[i], fBl, acc[i][j], 0, 0, 0);
            }
        }
        __syncthreads();
    }

    #pragma unroll
    for (int i = 0; i < 4; i++) {
        #pragma unroll
        for (int r = 0; r < 4; r++) {
            int u = u0 + wu * 64 + i * 16 + quad * 4 + r;
            if (u < U) {
                int lrow = topidx[b * U + u];
                #pragma unroll
                for (int j = 0; j < 4; j++) {
                    int dd = n0 + wd * 64 + j * 16 + lr;
                    unsafeAtomicAdd(&out[(size_t)b * perB + (size_t)lrow * 512 + dd],
                                    acc[i][j][r]);
                }
            }
        }
    }
}

// ---------------------------------------------------------------------------
extern "C" void kernel_launch(void* const* d_in, const int* in_sizes, int n_in,
                              void* d_out, int out_size, void* d_ws, size_t ws_size,
                              hipStream_t stream)
{
    const float* x1 = (const float*)d_in[0];
    const float* x2 = (const float*)d_in[1];
    const float* Wq = (const float*)d_in[2];
    const float* bq = (const float*)d_in[3];
    const float* Wk = (const float*)d_in[4];
    const float* bk = (const float*)d_in[5];
    const float* Wv = (const float*)d_in[6];
    const float* bv = (const float*)d_in[7];
    const int*  idx = (const int*)d_in[8];
    const int U = in_sizes[8];            // 450
    const int nst = (U + 127) / 128;      // 4

    float* out = (float*)d_out;

    const size_t perB = (size_t)D_DIM * L_DIM;          // 2,097,152
    const size_t tenH = (size_t)BATCH * perB;           // 33,554,432 halves
    _Float16* qh = (_Float16*)d_ws;
    _Float16* ql = qh + tenH;
    _Float16* kh = ql + tenH;
    _Float16* kl = kh + tenH;
    _Float16* vh = kl + tenH;
    _Float16* vl = vh + tenH;
    float* S = (float*)(vl + tenH);                     // 118 MB union region

    // proj-phase aliases inside S:
    _Float16* XTh = (_Float16*)S;
    _Float16* XTl = XTh + (size_t)8 * L_DIM * 512;
    _Float16* Wh  = XTl + (size_t)8 * L_DIM * 512;
    _Float16* Wl  = Wh + (size_t)3 * 512 * 512;

    // post-proj aliases inside S:
    _Float16* sh = (_Float16*)S;
    _Float16* sl = sh + (size_t)BATCH * (size_t)U * L_DIM;
    float* vmean = (float*)(sl + (size_t)BATCH * (size_t)U * L_DIM);
    float* partU = vmean + (size_t)BATCH * D_DIM;       // 2 MB scratch window
    float* vpart = partU;                               // vmean partials (1 MB)
    float* Mmax  = partU;                               // then qks partials (2 MB)
    float* Msum  = Mmax + (size_t)BATCH * nst * L_DIM;
    int* topidx  = (int*)(partU + (size_t)2 * BATCH * 4 * L_DIM);

    // 1. split W
    convert_w<<<dim3(1024, 3), 256, 0, stream>>>(Wq, Wk, Wv, Wh, Wl);

    // 2. projections (two 8-batch phases), outputs q/k/v as hi/lo fp16
    for (int phase = 0; phase < 2; phase++) {
        convert_x<<<dim3(64, 8, 8), 256, 0, stream>>>(x1, x2, XTh, XTl, phase);
        proj_mfma<<<dim3(L_DIM / 128, D_DIM / 128, 8 * 3), 256, 0, stream>>>(
            Wh, Wl, XTh, XTl, bq, bk, bv, qh, ql, kh, kl, vh, vl, phase);
    }

    // 3. v mean + output fill (vpart consumed before qks reuses the window)
    vmean_partial<<<dim3(32, BATCH), 512, 0, stream>>>(vh, vl, vpart);
    vmean_reduce<<<BATCH, 512, 0, stream>>>(vpart, vmean);
    fill_out<<<BATCH * 64, 256, 0, stream>>>(vmean, out);

    // 4. sampled QK^T partials (s-tile split) + top-U select
    qks_mfma<<<dim3(L_DIM / 128, nst, BATCH), 256, 0, stream>>>(
        qh, ql, kh, kl, idx, Mmax, Msum, U, nst);
    topk_select<<<BATCH, 512, 0, stream>>>(Mmax, Msum, topidx, U, nst);

    // 5. scores (h/l out), softmax, zero selected rows, attn @ V atomic scatter
    const int utiles = (U + 127) / 128;
    scores_mfma<<<dim3(L_DIM / 128, utiles, BATCH), 256, 0, stream>>>(
        qh, ql, kh, kl, topidx, sh, sl, U);
    softmax_hl<<<BATCH * U, 256, 0, stream>>>(sh, sl);
    zero_sel<<<dim3(U, BATCH), 256, 0, stream>>>(topidx, out, U);
    upd_mfma<<<dim3(utiles, D_DIM / 128, BATCH * KSPLIT), 256, 0, stream>>>(
        sh, sl, vh, vl, topidx, out, U);
}

// Round 5
// 931.482 us; speedup vs baseline: 3.2317x; 1.1814x over previous
//
#include <hip/hip_runtime.h>
#include <cstdint>
#include <cstddef>

#define L_DIM 4096
#define D_DIM 512
#define CIN   256
#define BATCH 16
#define KSPLIT 4

typedef _Float16 half8 __attribute__((ext_vector_type(8)));
typedef unsigned short ushort8 __attribute__((ext_vector_type(8)));
typedef float f32x4 __attribute__((ext_vector_type(4)));

__device__ __forceinline__ void gld16(const _Float16* g, _Float16* l) {
    __builtin_amdgcn_global_load_lds(
        (const __attribute__((address_space(1))) unsigned int*)g,
        (__attribute__((address_space(3))) unsigned int*)l,
        16, 0, 0);
}

// ---------------------------------------------------------------------------
// Split W (3 x 512x512 fp32) into fp16 hi/lo. grid (1024,3), block 256
// ---------------------------------------------------------------------------
__global__ __launch_bounds__(256) void convert_w(
    const float* __restrict__ Wq, const float* __restrict__ Wk,
    const float* __restrict__ Wv,
    _Float16* __restrict__ Wh, _Float16* __restrict__ Wl)
{
    const int w = blockIdx.y;
    const float* src = (w == 0) ? Wq : (w == 1) ? Wk : Wv;
    int i = blockIdx.x * 256 + threadIdx.x;
    float xv = src[i];
    _Float16 hi = (_Float16)xv;
    Wh[(size_t)w * 262144 + i] = hi;
    Wl[(size_t)w * 262144 + i] = (_Float16)(xv - (float)hi);
}

// ---------------------------------------------------------------------------
// Transpose + split X. Per phase 8 batches. grid (64, 8, 8), block 256.
// ---------------------------------------------------------------------------
__global__ __launch_bounds__(256) void convert_x(
    const float* __restrict__ x1, const float* __restrict__ x2,
    _Float16* __restrict__ XTh, _Float16* __restrict__ XTl, int phase)
{
    const int bb = blockIdx.z;
    const int b = phase * 8 + bb;
    const int s0 = blockIdx.x * 64;
    const int c0 = blockIdx.y * 64;
    __shared__ float t[64][65];
    const int tid = threadIdx.x;
    const int g = tid >> 6, sy = tid & 63;
    const float* src = (c0 < CIN)
        ? (x1 + (size_t)b * CIN * L_DIM + (size_t)c0 * L_DIM)
        : (x2 + (size_t)b * CIN * L_DIM + (size_t)(c0 - CIN) * L_DIM);
    #pragma unroll
    for (int r = 0; r < 16; r++) {
        int cl = g * 16 + r;
        t[cl][sy] = src[(size_t)cl * L_DIM + s0 + sy];
    }
    __syncthreads();
    _Float16* outh = XTh + (size_t)bb * L_DIM * 512 + (size_t)s0 * 512 + c0;
    _Float16* outl = XTl + (size_t)bb * L_DIM * 512 + (size_t)s0 * 512 + c0;
    #pragma unroll
    for (int r = 0; r < 16; r++) {
        int sl = g * 16 + r;
        float xv = t[sy][sl];
        _Float16 hi = (_Float16)xv;
        float lo = xv - (float)hi;
        outh[(size_t)sl * 512 + sy] = hi;
        outl[(size_t)sl * 512 + sy] = (_Float16)lo;
    }
}

// ---------------------------------------------------------------------------
// Projection via fp16x3 MFMA. q/k get hi+lo outputs; V gets hi only
// (error budget: lo(V) contributes ~2e-6 to out, threshold 6.7e-4).
// grid: (32, 4, 24), block 256
// ---------------------------------------------------------------------------
__global__ __launch_bounds__(256) void proj_mfma(
    const _Float16* __restrict__ Wh, const _Float16* __restrict__ Wl,
    const _Float16* __restrict__ XTh, const _Float16* __restrict__ XTl,
    const float* __restrict__ bq, const float* __restrict__ bk,
    const float* __restrict__ bv,
    _Float16* __restrict__ qh, _Float16* __restrict__ ql,
    _Float16* __restrict__ kh, _Float16* __restrict__ kl,
    _Float16* __restrict__ vh,
    int phase)
{
    const int z = blockIdx.z;
    const int bb = z / 3, w = z % 3;
    const int b = phase * 8 + bb;
    const _Float16* Ah_g = Wh + (size_t)w * 262144;
    const _Float16* Al_g = Wl + (size_t)w * 262144;
    const _Float16* Bh_g = XTh + (size_t)bb * ((size_t)L_DIM * 512);
    const _Float16* Bl_g = XTl + (size_t)bb * ((size_t)L_DIM * 512);
    const float* bias = (w == 0) ? bq : (w == 1) ? bk : bv;
    _Float16* outh = ((w == 0) ? qh : (w == 1) ? kh : vh) + (size_t)b * ((size_t)D_DIM * L_DIM);
    _Float16* outl = ((w == 0) ? ql : (w == 1) ? kl : (_Float16*)0);
    if (outl) outl += (size_t)b * ((size_t)D_DIM * L_DIM);

    const int m0 = blockIdx.y * 128;
    const int n0 = blockIdx.x * 128;

    __shared__ _Float16 lds[4 * 128 * 32];
    _Float16* ldsA_h = lds;
    _Float16* ldsA_l = lds + 4096;
    _Float16* ldsB_h = lds + 8192;
    _Float16* ldsB_l = lds + 12288;

    const int tid = threadIdx.x;
    const int w4 = tid >> 6, lane = tid & 63;
    const int lr = lane & 15, quad = lane >> 4;
    const int wr = w4 >> 1, wc = w4 & 1;

    f32x4 acc[4][4] = {};

    const int q1 = w4 * 128 + lane, q2 = q1 + 64;
    const int r1 = q1 >> 2, c41 = q1 & 3;
    const int r2 = q2 >> 2, c42 = q2 & 3;

    const _Float16* pAh1 = Ah_g + (size_t)(m0 + r1) * 512 + c41 * 8;
    const _Float16* pAh2 = Ah_g + (size_t)(m0 + r2) * 512 + c42 * 8;
    const _Float16* pAl1 = Al_g + (size_t)(m0 + r1) * 512 + c41 * 8;
    const _Float16* pAl2 = Al_g + (size_t)(m0 + r2) * 512 + c42 * 8;
    const _Float16* pBh1 = Bh_g + (size_t)(n0 + r1) * 512 + c41 * 8;
    const _Float16* pBh2 = Bh_g + (size_t)(n0 + r2) * 512 + c42 * 8;
    const _Float16* pBl1 = Bl_g + (size_t)(n0 + r1) * 512 + c41 * 8;
    const _Float16* pBl2 = Bl_g + (size_t)(n0 + r2) * 512 + c42 * 8;

    _Float16* d1 = (_Float16*)(lds) + (size_t)(w4 * 128) * 8;
    _Float16* d2 = (_Float16*)(lds) + (size_t)(w4 * 128 + 64) * 8;

    for (int k0 = 0; k0 < 512; k0 += 32) {
        if (k0) __syncthreads();
        gld16(pAh1 + k0, d1);
        gld16(pAh2 + k0, d2);
        gld16(pAl1 + k0, d1 + 4096);
        gld16(pAl2 + k0, d2 + 4096);
        gld16(pBh1 + k0, d1 + 8192);
        gld16(pBh2 + k0, d2 + 8192);
        gld16(pBl1 + k0, d1 + 12288);
        gld16(pBl2 + k0, d2 + 12288);
        __syncthreads();

        half8 fAh[4], fAl[4];
        #pragma unroll
        for (int i = 0; i < 4; i++) {
            int m = wr * 64 + i * 16 + lr;
            fAh[i] = *(const half8*)(ldsA_h + m * 32 + quad * 8);
            fAl[i] = *(const half8*)(ldsA_l + m * 32 + quad * 8);
        }
        #pragma unroll
        for (int j = 0; j < 4; j++) {
            int n = wc * 64 + j * 16 + lr;
            half8 fBh = *(const half8*)(ldsB_h + n * 32 + quad * 8);
            half8 fBl = *(const half8*)(ldsB_l + n * 32 + quad * 8);
            #pragma unroll
            for (int i = 0; i < 4; i++) {
                acc[i][j] = __builtin_amdgcn_mfma_f32_16x16x32_f16(fAh[i], fBh, acc[i][j], 0, 0, 0);
                acc[i][j] = __builtin_amdgcn_mfma_f32_16x16x32_f16(fAl[i], fBh, acc[i][j], 0, 0, 0);
                acc[i][j] = __builtin_amdgcn_mfma_f32_16x16x32_f16(fAh[i], fBl, acc[i][j], 0, 0, 0);
            }
        }
    }

    #pragma unroll
    for (int i = 0; i < 4; i++) {
        int mg = m0 + wr * 64 + i * 16 + quad * 4;
        #pragma unroll
        for (int r = 0; r < 4; r++) {
            float bvv = bias[mg + r];
            #pragma unroll
            for (int j = 0; j < 4; j++) {
                int ng = n0 + wc * 64 + j * 16 + lr;
                float val = acc[i][j][r] + bvv;
                _Float16 hi = (_Float16)val;
                size_t off = (size_t)(mg + r) * L_DIM + ng;
                outh[off] = hi;
                if (w != 2) outl[off] = (_Float16)(val - (float)hi);
            }
        }
    }
}

// ---------------------------------------------------------------------------
// qks via fp16x3 MFMA, one s-tile per block, partial max/sum out.
// (kept at x3 precision: M-gaps at the top-k boundary are ~1e-3)
// grid: (32 l-tiles, nst s-tiles, 16 b), block 256
// ---------------------------------------------------------------------------
__global__ __launch_bounds__(256) void qks_mfma(
    const _Float16* __restrict__ qh, const _Float16* __restrict__ ql,
    const _Float16* __restrict__ kh, const _Float16* __restrict__ kl,
    const int* __restrict__ idx_sample,
    float* __restrict__ Mmax, float* __restrict__ Msum, int U, int nst)
{
    const int b = blockIdx.z;
    const int stile = blockIdx.y;
    const int l0 = blockIdx.x * 128;
    const int s0 = stile * 128;
    const size_t perB = (size_t)D_DIM * L_DIM;
    const _Float16* qh_b = qh + (size_t)b * perB;
    const _Float16* ql_b = ql + (size_t)b * perB;
    const _Float16* kh_b = kh + (size_t)b * perB;
    const _Float16* kl_b = kl + (size_t)b * perB;

    __shared__ _Float16 ldsAh[4096], ldsAl[4096];   // gathered k [s][32]
    __shared__ _Float16 ldsBh[4096], ldsBl[4096];   // q [l][32]
    __shared__ int sidx[128];
    __shared__ float redm[8][128];
    __shared__ float reds[8][128];

    const int tid = threadIdx.x;
    const int w4 = tid >> 6, lane = tid & 63;
    const int lr = lane & 15, quad = lane >> 4;
    const int ws = w4 >> 1, wl = w4 & 1;

    if (tid < 128) {
        int s = s0 + tid;
        sidx[tid] = (s < U) ? idx_sample[s] : idx_sample[0];
    }
    __syncthreads();

    f32x4 acc[4][4] = {};

    for (int k0 = 0; k0 < 512; k0 += 32) {
        #pragma unroll
        for (int t = 0; t < 2; t++) {
            int c = w4 * 128 + t * 64 + lane;
            int row = c >> 2, part = c & 3;
            int krow = sidx[row];
            size_t go = (size_t)krow * 512 + k0 + part * 8;
            size_t qo = (size_t)(l0 + row) * 512 + k0 + part * 8;
            int base = (w4 * 128 + t * 64) * 8;
            gld16(kh_b + go, ldsAh + base);
            gld16(kl_b + go, ldsAl + base);
            gld16(qh_b + qo, ldsBh + base);
            gld16(ql_b + qo, ldsBl + base);
        }
        __syncthreads();

        half8 fAh[4], fAl[4];
        #pragma unroll
        for (int i = 0; i < 4; i++) {
            int s = ws * 64 + i * 16 + lr;
            fAh[i] = *(const half8*)(ldsAh + s * 32 + quad * 8);
            fAl[i] = *(const half8*)(ldsAl + s * 32 + quad * 8);
        }
        #pragma unroll
        for (int j = 0; j < 4; j++) {
            int l = wl * 64 + j * 16 + lr;
            half8 fBh = *(const half8*)(ldsBh + l * 32 + quad * 8);
            half8 fBl = *(const half8*)(ldsBl + l * 32 + quad * 8);
            #pragma unroll
            for (int i = 0; i < 4; i++) {
                acc[i][j] = __builtin_amdgcn_mfma_f32_16x16x32_f16(fAh[i], fBh, acc[i][j], 0, 0, 0);
                acc[i][j] = __builtin_amdgcn_mfma_f32_16x16x32_f16(fAl[i], fBh, acc[i][j], 0, 0, 0);
                acc[i][j] = __builtin_amdgcn_mfma_f32_16x16x32_f16(fAh[i], fBl, acc[i][j], 0, 0, 0);
            }
        }
        __syncthreads();
    }

    float runmax[4], runsum[4];
    #pragma unroll
    for (int j = 0; j < 4; j++) { runmax[j] = -__builtin_inff(); runsum[j] = 0.f; }
    #pragma unroll
    for (int i = 0; i < 4; i++) {
        #pragma unroll
        for (int r = 0; r < 4; r++) {
            int sg = s0 + ws * 64 + i * 16 + quad * 4 + r;
            if (sg < U) {
                #pragma unroll
                for (int j = 0; j < 4; j++) {
                    runmax[j] = fmaxf(runmax[j], acc[i][j][r]);
                    runsum[j] += acc[i][j][r];
                }
            }
        }
    }
    #pragma unroll
    for (int j = 0; j < 4; j++) {
        int l = wl * 64 + j * 16 + lr;
        redm[ws * 4 + quad][l] = runmax[j];
        reds[ws * 4 + quad][l] = runsum[j];
    }
    __syncthreads();
    if (tid < 128) {
        float gm = -__builtin_inff(), gs = 0.f;
        #pragma unroll
        for (int t = 0; t < 8; t++) { gm = fmaxf(gm, redm[t][tid]); gs += reds[t][tid]; }
        size_t o = ((size_t)b * nst + stile) * L_DIM + l0 + tid;
        Mmax[o] = gm;
        Msum[o] = gs;
    }
}

// ---------------------------------------------------------------------------
// Per-batch top-U: reduce partials -> M, binary-search threshold on key bits,
// compact indices (set semantics). grid (B), block 512.
// ---------------------------------------------------------------------------
__global__ __launch_bounds__(512) void topk_select(
    const float* __restrict__ Mmax, const float* __restrict__ Msum,
    int* __restrict__ topidx, int U, int nst)
{
    const int b = blockIdx.x;
    const int tid = threadIdx.x;
    __shared__ int wcnt[8];
    __shared__ int basec;

    unsigned mykey[8];
    #pragma unroll
    for (int t = 0; t < 8; t++) {
        int l = t * 512 + tid;
        float gm = -__builtin_inff(), gs = 0.f;
        for (int st = 0; st < nst; st++) {
            size_t o = ((size_t)b * nst + st) * L_DIM + l;
            gm = fmaxf(gm, Mmax[o]);
            gs += Msum[o];
        }
        float M = gm - gs * (1.f / (float)L_DIM);
        unsigned bits = __float_as_uint(M);
        mykey[t] = (bits & 0x80000000u) ? ~bits : (bits | 0x80000000u);
    }
    if (tid == 0) basec = 0;

    const int wv = tid >> 6, lane = tid & 63;
    unsigned lo = 0u, hi = 0xFFFFFFFFu;
    while (lo < hi) {
        unsigned hl = hi - lo;
        unsigned mid = lo + (hl >> 1) + (hl & 1u);   // ceil midpoint, overflow-safe
        int c = 0;
        #pragma unroll
        for (int t = 0; t < 8; t++) c += (mykey[t] >= mid) ? 1 : 0;
        #pragma unroll
        for (int o = 32; o > 0; o >>= 1) c += __shfl_down(c, o, 64);
        if (lane == 0) wcnt[wv] = c;
        __syncthreads();
        int total = 0;
        #pragma unroll
        for (int i = 0; i < 8; i++) total += wcnt[i];
        if (total >= U) lo = mid; else hi = mid - 1;
        __syncthreads();
    }
    #pragma unroll
    for (int t = 0; t < 8; t++) {
        if (mykey[t] >= lo) {
            int pos = atomicAdd(&basec, 1);
            if (pos < U) topidx[b * U + pos] = t * 512 + tid;
        }
    }
}

// ---------------------------------------------------------------------------
// v mean from v_h (lo part of v is never stored; error ~2e-5)
// ---------------------------------------------------------------------------
__global__ __launch_bounds__(512) void vmean_partial(
    const _Float16* __restrict__ vh, float* __restrict__ partial)
{
    const int ch = blockIdx.x, b = blockIdx.y;
    const int d = threadIdx.x;
    const _Float16* vhb = vh + (size_t)b * ((size_t)D_DIM * L_DIM);
    float acc = 0.f;
    const int lbeg = ch * 128;
    for (int l = lbeg; l < lbeg + 128; l++)
        acc += (float)vhb[(size_t)l * D_DIM + d];
    partial[((size_t)b * 32 + ch) * D_DIM + d] = acc;
}

__global__ __launch_bounds__(512) void vmean_reduce(const float* __restrict__ partial,
                                                    float* __restrict__ vmean)
{
    const int b = blockIdx.x;
    const int d = threadIdx.x;
    float acc = 0.f;
    for (int ch = 0; ch < 32; ch++) acc += partial[((size_t)b * 32 + ch) * D_DIM + d];
    vmean[b * D_DIM + d] = acc * (1.f / (float)L_DIM);
}

__global__ __launch_bounds__(256) void fill_out(const float* __restrict__ vmean,
                                                float* __restrict__ out)
{
    const int z = blockIdx.x;
    const int b = z >> 6, lch = z & 63;
    __shared__ float vm[512];
    vm[threadIdx.x] = vmean[b * 512 + threadIdx.x];
    vm[threadIdx.x + 256] = vmean[b * 512 + threadIdx.x + 256];
    __syncthreads();
    float* op = out + (size_t)b * ((size_t)D_DIM * L_DIM) + (size_t)lch * 64 * 512;
    #pragma unroll
    for (int it = 0; it < 32; it++) {
        int flat = (threadIdx.x + it * 256) * 4;
        int d = flat & 511;
        float4 r = { vm[d], vm[d + 1], vm[d + 2], vm[d + 3] };
        *(float4*)&op[flat] = r;
    }
}

// Zero selected output rows ahead of atomic accumulation. grid (U, B), block 256
__global__ __launch_bounds__(256) void zero_sel(const int* __restrict__ topidx,
                                                float* __restrict__ out, int U)
{
    const int u = blockIdx.x, b = blockIdx.y;
    int row = topidx[b * U + u];
    float2 z = { 0.f, 0.f };
    *(float2*)&out[(size_t)b * ((size_t)D_DIM * L_DIM) + (size_t)row * 512
                   + threadIdx.x * 2] = z;
}

// ---------------------------------------------------------------------------
// scores via SINGLE fp16 MFMA (softmax logit noise ~1.4e-4 -> out ~1e-6).
// C[u][s] = scale * q_h[top_u] . k_h[s], out fp16.
// grid: (32 s-tiles, (U+127)/128 u-tiles, 16 b), block 256
// ---------------------------------------------------------------------------
__global__ __launch_bounds__(256) void scores_mfma(
    const _Float16* __restrict__ qh, const _Float16* __restrict__ kh,
    const int* __restrict__ topidx,
    _Float16* __restrict__ sh, int U)
{
    const int b = blockIdx.z;
    const int s0 = blockIdx.x * 128;
    const int u0 = blockIdx.y * 128;
    const size_t perB = (size_t)D_DIM * L_DIM;
    const _Float16* qh_b = qh + (size_t)b * perB;
    const _Float16* kh_b = kh + (size_t)b * perB;
    _Float16* sh_b = sh + (size_t)b * (size_t)U * L_DIM;

    __shared__ _Float16 ldsAh[4096];   // gathered q [u][32]
    __shared__ _Float16 ldsBh[4096];   // k [s][32]
    __shared__ int arow[128];

    const int tid = threadIdx.x;
    const int w4 = tid >> 6, lane = tid & 63;
    const int lr = lane & 15, quad = lane >> 4;
    const int wu = w4 >> 1, wn = w4 & 1;

    if (tid < 128) {
        int u = u0 + tid;
        arow[tid] = topidx[b * U + (u < U ? u : U - 1)];
    }
    __syncthreads();

    f32x4 acc[4][4] = {};

    for (int k0 = 0; k0 < 512; k0 += 32) {
        #pragma unroll
        for (int t = 0; t < 2; t++) {
            int c = w4 * 128 + t * 64 + lane;
            int row = c >> 2, part = c & 3;
            size_t go = (size_t)arow[row] * 512 + k0 + part * 8;
            size_t ko = (size_t)(s0 + row) * 512 + k0 + part * 8;
            int base = (w4 * 128 + t * 64) * 8;
            gld16(qh_b + go, ldsAh + base);
            gld16(kh_b + ko, ldsBh + base);
        }
        __syncthreads();

        half8 fAh[4];
        #pragma unroll
        for (int i = 0; i < 4; i++) {
            int u = wu * 64 + i * 16 + lr;
            fAh[i] = *(const half8*)(ldsAh + u * 32 + quad * 8);
        }
        #pragma unroll
        for (int j = 0; j < 4; j++) {
            int s = wn * 64 + j * 16 + lr;
            half8 fBh = *(const half8*)(ldsBh + s * 32 + quad * 8);
            #pragma unroll
            for (int i = 0; i < 4; i++)
                acc[i][j] = __builtin_amdgcn_mfma_f32_16x16x32_f16(fAh[i], fBh, acc[i][j], 0, 0, 0);
        }
        __syncthreads();
    }

    const float scale = 0.044194173824159216f;   // 1/sqrt(512)
    #pragma unroll
    for (int i = 0; i < 4; i++) {
        #pragma unroll
        for (int r = 0; r < 4; r++) {
            int u = u0 + wu * 64 + i * 16 + quad * 4 + r;
            if (u < U) {
                #pragma unroll
                for (int j = 0; j < 4; j++) {
                    int s = s0 + wn * 64 + j * 16 + lr;
                    sh_b[(size_t)u * L_DIM + s] = (_Float16)(acc[i][j][r] * scale);
                }
            }
        }
    }
}

// ---------------------------------------------------------------------------
// Row softmax over 4096, fp16 in/out (in place). grid (B*U), block 256
// ---------------------------------------------------------------------------
__global__ __launch_bounds__(256) void softmax_h(_Float16* __restrict__ sh)
{
    _Float16* hrow = sh + (size_t)blockIdx.x * L_DIM;
    const int tid = threadIdx.x;
    float x[16];
    #pragma unroll
    for (int t = 0; t < 2; t++) {
        half8 h8 = *(const half8*)(hrow + tid * 8 + t * 2048);
        #pragma unroll
        for (int i = 0; i < 8; i++) x[t * 8 + i] = (float)h8[i];
    }
    __shared__ float red[256];
    float lm = -__builtin_inff();
    #pragma unroll
    for (int i = 0; i < 16; i++) lm = fmaxf(lm, x[i]);
    red[tid] = lm;
    __syncthreads();
    for (int o = 128; o > 0; o >>= 1) {
        if (tid < o) red[tid] = fmaxf(red[tid], red[tid + o]);
        __syncthreads();
    }
    float m = red[0];
    __syncthreads();
    float ls = 0.f;
    #pragma unroll
    for (int i = 0; i < 16; i++) { x[i] = __expf(x[i] - m); ls += x[i]; }
    red[tid] = ls;
    __syncthreads();
    for (int o = 128; o > 0; o >>= 1) {
        if (tid < o) red[tid] += red[tid + o];
        __syncthreads();
    }
    float inv = 1.f / red[0];
    #pragma unroll
    for (int t = 0; t < 2; t++) {
        half8 h8;
        #pragma unroll
        for (int i = 0; i < 8; i++) h8[i] = (_Float16)(x[t * 8 + i] * inv);
        *(half8*)(hrow + tid * 8 + t * 2048) = h8;
    }
}

// ---------------------------------------------------------------------------
// upd via SINGLE fp16 MFMA, K-split x4, atomic accumulate into zeroed rows.
// A = attn fp16 (k-contig), B = v_h tiles transposed in LDS (chunk swizzle).
// grid: ((U+127)/128 u-tiles, 4 dd-tiles, 16*KSPLIT), block 256
// ---------------------------------------------------------------------------
__global__ __launch_bounds__(256) void upd_mfma(
    const _Float16* __restrict__ sh, const _Float16* __restrict__ vh,
    const int* __restrict__ topidx, float* __restrict__ out, int U)
{
    const int zz = blockIdx.z;
    const int b = zz >> 2, ks = zz & 3;
    const int n0 = blockIdx.y * 128;
    const int u0 = blockIdx.x * 128;
    const size_t perB = (size_t)D_DIM * L_DIM;
    const _Float16* ah_b = sh + (size_t)b * (size_t)U * L_DIM;
    const _Float16* vh_b = vh + (size_t)b * perB;

    __shared__ _Float16 ldsAh[4096];   // attn [u][32]
    __shared__ _Float16 ldsBh[4096];   // vT   [dd][32] (chunk-swizzled)

    const int tid = threadIdx.x;
    const int w4 = tid >> 6, lane = tid & 63;
    const int lr = lane & 15, quad = lane >> 4;
    const int wu = w4 >> 1, wd = w4 & 1;

    const int part = tid & 15, spair = tid >> 4;
    const int s_b = spair * 2;
    const int colw = ((spair >> 2) + part) & 3;
    const int so2 = (s_b & 7);

    f32x4 acc[4][4] = {};

    const int kbeg = ks * (L_DIM / KSPLIT);
    const int kend = kbeg + (L_DIM / KSPLIT);
    for (int k0 = kbeg; k0 < kend; k0 += 32) {
        #pragma unroll
        for (int t = 0; t < 2; t++) {
            int c = w4 * 128 + t * 64 + lane;
            int u = c >> 2, pt = c & 3;
            int urow = u0 + u; if (urow >= U) urow = U - 1;
            size_t ao = (size_t)urow * L_DIM + k0 + pt * 8;
            int base = (w4 * 128 + t * 64) * 8;
            gld16(ah_b + ao, ldsAh + base);
        }
        {
            const _Float16* s0p = vh_b + (size_t)(k0 + s_b) * 512 + n0 + part * 8;
            const _Float16* s1p = s0p + 512;
            ushort8 a0 = *(const ushort8*)s0p;
            ushort8 a1 = *(const ushort8*)s1p;
            #pragma unroll
            for (int t = 0; t < 8; t++) {
                int dd = part * 8 + t;
                unsigned int ph = (unsigned int)a0[t] | ((unsigned int)a1[t] << 16);
                *(unsigned int*)(ldsBh + dd * 32 + colw * 8 + so2) = ph;
            }
        }
        __syncthreads();

        half8 fAh[4];
        #pragma unroll
        for (int i = 0; i < 4; i++) {
            int u = wu * 64 + i * 16 + lr;
            fAh[i] = *(const half8*)(ldsAh + u * 32 + quad * 8);
        }
        #pragma unroll
        for (int j = 0; j < 4; j++) {
            int dd = wd * 64 + j * 16 + lr;
            int col = (quad + (dd >> 3)) & 3;
            half8 fBh = *(const half8*)(ldsBh + dd * 32 + col * 8);
            #pragma unroll
            for (int i = 0; i < 4; i++)
                acc[i][j] = __builtin_amdgcn_mfma_f32_16x16x32_f16(fAh[i], fBh, acc[i][j], 0, 0, 0);
        }
        __syncthreads();
    }

    #pragma unroll
    for (int i = 0; i < 4; i++) {
        #pragma unroll
        for (int r = 0; r < 4; r++) {
            int u = u0 + wu * 64 + i * 16 + quad * 4 + r;
            if (u < U) {
                int lrow = topidx[b * U + u];
                #pragma unroll
                for (int j = 0; j < 4; j++) {
                    int dd = n0 + wd * 64 + j * 16 + lr;
                    unsafeAtomicAdd(&out[(size_t)b * perB + (size_t)lrow * 512 + dd],
                                    acc[i][j][r]);
                }
            }
        }
    }
}

// ---------------------------------------------------------------------------
extern "C" void kernel_launch(void* const* d_in, const int* in_sizes, int n_in,
                              void* d_out, int out_size, void* d_ws, size_t ws_size,
                              hipStream_t stream)
{
    const float* x1 = (const float*)d_in[0];
    const float* x2 = (const float*)d_in[1];
    const float* Wq = (const float*)d_in[2];
    const float* bq = (const float*)d_in[3];
    const float* Wk = (const float*)d_in[4];
    const float* bk = (const float*)d_in[5];
    const float* Wv = (const float*)d_in[6];
    const float* bv = (const float*)d_in[7];
    const int*  idx = (const int*)d_in[8];
    const int U = in_sizes[8];            // 450
    const int nst = (U + 127) / 128;      // 4

    float* out = (float*)d_out;

    const size_t perB = (size_t)D_DIM * L_DIM;          // 2,097,152
    const size_t tenH = (size_t)BATCH * perB;           // 33,554,432 halves
    _Float16* qh = (_Float16*)d_ws;
    _Float16* ql = qh + tenH;
    _Float16* kh = ql + tenH;
    _Float16* kl = kh + tenH;
    _Float16* vh = kl + tenH;
    float* S = (float*)(vh + tenH);                     // union region (~202 MB)

    // proj-phase aliases inside S:
    _Float16* XTh = (_Float16*)S;
    _Float16* XTl = XTh + (size_t)8 * L_DIM * 512;
    _Float16* Wh  = XTl + (size_t)8 * L_DIM * 512;
    _Float16* Wl  = Wh + (size_t)3 * 512 * 512;

    // post-proj aliases inside S:
    _Float16* sh = (_Float16*)S;
    float* vmean = (float*)(sh + (size_t)BATCH * (size_t)U * L_DIM);
    float* partU = vmean + (size_t)BATCH * D_DIM;       // 2 MB scratch window
    float* vpart = partU;                               // vmean partials (1 MB)
    float* Mmax  = partU;                               // then qks partials (2 MB)
    float* Msum  = Mmax + (size_t)BATCH * nst * L_DIM;
    int* topidx  = (int*)(partU + (size_t)2 * BATCH * 4 * L_DIM);

    // 1. split W
    convert_w<<<dim3(1024, 3), 256, 0, stream>>>(Wq, Wk, Wv, Wh, Wl);

    // 2. projections (two 8-batch phases): q/k hi+lo, v hi only
    for (int phase = 0; phase < 2; phase++) {
        convert_x<<<dim3(64, 8, 8), 256, 0, stream>>>(x1, x2, XTh, XTl, phase);
        proj_mfma<<<dim3(L_DIM / 128, D_DIM / 128, 8 * 3), 256, 0, stream>>>(
            Wh, Wl, XTh, XTl, bq, bk, bv, qh, ql, kh, kl, vh, phase);
    }

    // 3. v mean + output fill
    vmean_partial<<<dim3(32, BATCH), 512, 0, stream>>>(vh, vpart);
    vmean_reduce<<<BATCH, 512, 0, stream>>>(vpart, vmean);
    fill_out<<<BATCH * 64, 256, 0, stream>>>(vmean, out);

    // 4. sampled QK^T partials (s-tile split) + top-U select
    qks_mfma<<<dim3(L_DIM / 128, nst, BATCH), 256, 0, stream>>>(
        qh, ql, kh, kl, idx, Mmax, Msum, U, nst);
    topk_select<<<BATCH, 512, 0, stream>>>(Mmax, Msum, topidx, U, nst);

    // 5. scores (fp16), softmax, zero selected rows, attn @ V atomic scatter
    const int utiles = (U + 127) / 128;
    scores_mfma<<<dim3(L_DIM / 128, utiles, BATCH), 256, 0, stream>>>(
        qh, kh, topidx, sh, U);
    softmax_h<<<BATCH * U, 256, 0, stream>>>(sh);
    zero_sel<<<dim3(U, BATCH), 256, 0, stream>>>(topidx, out, U);
    upd_mfma<<<dim3(utiles, D_DIM / 128, BATCH * KSPLIT), 256, 0, stream>>>(
        sh, vh, topidx, out, U);
}